// Round 4
// baseline (1566.153 us; speedup 1.0000x reference)
//
#include <hip/hip_runtime.h>
#include <cstdint>
#include <cstddef>

// ---------------- problem geometry ----------------
#define H_DIM   2560
#define DINNER  8192
#define GHEADS  32
#define DGATE   4096
#define DH      128
#define BSZ     2
#define LSEQ    4096
#define MROWS   (BSZ*LSEQ)     // 8192 token rows
#define NXP     4224           // precise out width: 4096 x | 32 B | 32 C | 64 pad
#define NCHUNK  64
#define SCHUNK  (LSEQ/NCHUNK)  // 64

typedef __attribute__((ext_vector_type(4))) float  f32x4;
typedef __attribute__((ext_vector_type(8))) __bf16 bf16x8;
typedef unsigned short u16;
typedef unsigned int   u32;

static __device__ __forceinline__ u16 f2bf(float f) {
  union { float f; u32 u; } v; v.f = f;
  u32 r = v.u + 0x7fffu + ((v.u >> 16) & 1u);   // RNE
  return (u16)(r >> 16);
}
static __device__ __forceinline__ float bf2f(u16 u) {
  union { u32 u; float f; } v; v.u = ((u32)u) << 16;
  return v.f;
}
static __device__ __forceinline__ float silu(float x) {
  return x / (1.0f + expf(-x));
}

// ---------------- prep casts ----------------
__global__ void cast_f32_bf16(const float* __restrict__ in, u16* __restrict__ out, int n4) {
  int i = blockIdx.x * blockDim.x + threadIdx.x;
  if (i < n4) {
    f32x4 v = ((const f32x4*)in)[i];
    u32 p0 = (u32)f2bf(v[0]) | ((u32)f2bf(v[1]) << 16);
    u32 p1 = (u32)f2bf(v[2]) | ((u32)f2bf(v[3]) << 16);
    ((uint2*)out)[i] = make_uint2(p0, p1);
  }
}

// split f32 -> hi bf16 + lo bf16 (lo = RNE(x - hi)); done ONCE (was per N-block in-GEMM)
__global__ void cast_split(const float* __restrict__ in, u16* __restrict__ hi,
                           u16* __restrict__ lo, int n4) {
  int i = blockIdx.x * blockDim.x + threadIdx.x;
  if (i < n4) {
    f32x4 v = ((const f32x4*)in)[i];
    u16 h[4], l[4];
#pragma unroll
    for (int j = 0; j < 4; j++) {
      h[j] = f2bf(v[j]);
      l[j] = f2bf(v[j] - bf2f(h[j]));
    }
    ((uint2*)hi)[i] = make_uint2((u32)h[0] | ((u32)h[1] << 16), (u32)h[2] | ((u32)h[3] << 16));
    ((uint2*)lo)[i] = make_uint2((u32)l[0] | ((u32)l[1] << 16), (u32)l[2] | ((u32)l[3] << 16));
  }
}

// wc_hi rows: 0..4095 = Wqkv x-rows, 4096..8191 = Wqkv z-rows, 8192..8223 = Wb,
//             8224..8255 = Wa, 8256..8319 = 0
// wc_lo rows: 0..4095 = lo(x-rows), 4096..4127 = lo(Wb), 4128..4159 = lo(Wa), 4160..4223 = 0
__global__ void build_wc_split(const float* __restrict__ Wqkv, const float* __restrict__ Wb,
                               const float* __restrict__ Wa, u16* __restrict__ hi,
                               u16* __restrict__ lo) {
  int row = blockIdx.x;              // 0..8319
  const float* src = nullptr;
  if (row < DINNER)            src = Wqkv + (size_t)row * H_DIM;
  else if (row < DINNER + 32)  src = Wb + (size_t)(row - DINNER) * H_DIM;
  else if (row < DINNER + 64)  src = Wa + (size_t)(row - DINNER - 32) * H_DIM;
  const bool has_lo = (row < 4096) || (row >= DINNER);
  u16* oh = hi + (size_t)row * H_DIM;
  u16* ol = has_lo ? (lo + (size_t)(row < 4096 ? row : row - 4096) * H_DIM) : nullptr;
  for (int i = threadIdx.x; i < H_DIM / 4; i += blockDim.x) {
    u16 h[4] = {0, 0, 0, 0}, l[4] = {0, 0, 0, 0};
    if (src) {
      f32x4 v = ((const f32x4*)src)[i];
#pragma unroll
      for (int j = 0; j < 4; j++) {
        h[j] = f2bf(v[j]);
        l[j] = f2bf(v[j] - bf2f(h[j]));
      }
    }
    ((uint2*)oh)[i] = make_uint2((u32)h[0] | ((u32)h[1] << 16), (u32)h[2] | ((u32)h[3] << 16));
    if (ol)
      ((uint2*)ol)[i] = make_uint2((u32)l[0] | ((u32)l[1] << 16), (u32)l[2] | ((u32)l[3] << 16));
  }
}

// ---------------- GEMM helpers ----------------
static __device__ __forceinline__ void gload16(const u16* g, u16* l) {
  __builtin_amdgcn_global_load_lds(
      (const __attribute__((address_space(1))) u32*)g,
      (__attribute__((address_space(3))) u32*)l, 16, 0, 0);
}

// plain 1-product GEMM: C[m,n] = sum_k A[m,k]*Bt[n,k]; bf16 in. Grid (N/128, M/128), 256 thr.
template<bool OUT_BF16>
__global__ __launch_bounds__(256)
void gemm_bt128(const u16* __restrict__ A, const u16* __restrict__ Bt,
                void* __restrict__ Cout, int K, int ldc) {
  __shared__ __align__(16) u16 As[128 * 32];
  __shared__ __align__(16) u16 Bs[128 * 32];
  const int tid  = threadIdx.x;
  const int lane = tid & 63;
  const int wave = tid >> 6;
  const int wm = (wave & 1) * 64;
  const int wn = (wave >> 1) * 64;
  const size_t bm = (size_t)blockIdx.y * 128;
  const size_t bn = (size_t)blockIdx.x * 128;

  const int chunk0 = wave * 2, chunk1 = wave * 2 + 1;
  const int e0 = chunk0 * 512 + lane * 8;
  const int e1 = chunk1 * 512 + lane * 8;
  const int r0 = e0 >> 5, c0 = e0 & 31;
  const int r1 = e1 >> 5, c1 = e1 & 31;
  const u16* Ab = A + bm * (size_t)K;
  const u16* Bb = Bt + bn * (size_t)K;

  f32x4 acc[4][4];
#pragma unroll
  for (int i = 0; i < 4; i++)
#pragma unroll
    for (int j = 0; j < 4; j++) acc[i][j] = (f32x4){0.f, 0.f, 0.f, 0.f};

  for (int k0 = 0; k0 < K; k0 += 32) {
    gload16(Ab + (size_t)r0 * K + k0 + c0, &As[chunk0 * 512]);
    gload16(Ab + (size_t)r1 * K + k0 + c1, &As[chunk1 * 512]);
    gload16(Bb + (size_t)r0 * K + k0 + c0, &Bs[chunk0 * 512]);
    gload16(Bb + (size_t)r1 * K + k0 + c1, &Bs[chunk1 * 512]);
    __syncthreads();
    const int fr = lane & 15, fk = (lane >> 4) * 8;
    bf16x8 av[4], bv[4];
#pragma unroll
    for (int i = 0; i < 4; i++) av[i] = *(const bf16x8*)&As[(wm + i * 16 + fr) * 32 + fk];
#pragma unroll
    for (int j = 0; j < 4; j++) bv[j] = *(const bf16x8*)&Bs[(wn + j * 16 + fr) * 32 + fk];
#pragma unroll
    for (int i = 0; i < 4; i++)
#pragma unroll
      for (int j = 0; j < 4; j++)
        acc[i][j] = __builtin_amdgcn_mfma_f32_16x16x32_bf16(av[i], bv[j], acc[i][j], 0, 0, 0);
    __syncthreads();
  }
  const int cr = (lane >> 4) * 4, ccol = lane & 15;
#pragma unroll
  for (int i = 0; i < 4; i++)
#pragma unroll
    for (int j = 0; j < 4; j++)
#pragma unroll
      for (int r = 0; r < 4; r++) {
        size_t row = bm + wm + i * 16 + cr + r;
        size_t col = bn + wn + j * 16 + ccol;
        if (OUT_BF16) ((u16*)Cout)[row * ldc + col] = f2bf(acc[i][j][r]);
        else          ((float*)Cout)[row * ldc + col] = acc[i][j][r];
      }
}

// precise 3-product GEMM for x|B|C: acc += Ah*Bh + Ah*Bl + Al*Bh; f32 out.
// All four tiles staged via global_load_lds (A pre-split into hs_hi/hs_lo).
// Grid (33, 64): bx<32 -> x tiles, bx==32 -> B/C tile.
__global__ __launch_bounds__(256)
void gemm_precise(const u16* __restrict__ Ah, const u16* __restrict__ Al,
                  const u16* __restrict__ Bh, const u16* __restrict__ Bl,
                  float* __restrict__ Cout) {
  __shared__ __align__(16) u16 Ash[128 * 32];
  __shared__ __align__(16) u16 Asl[128 * 32];
  __shared__ __align__(16) u16 Bsh[128 * 32];
  __shared__ __align__(16) u16 Bsl[128 * 32];
  const int K = H_DIM;
  const int tid  = threadIdx.x;
  const int lane = tid & 63;
  const int wave = tid >> 6;
  const int wm = (wave & 1) * 64;
  const int wn = (wave >> 1) * 64;
  const size_t bm = (size_t)blockIdx.y * 128;
  const int bx = blockIdx.x;
  const size_t wrow_hi = (bx < 32) ? (size_t)bx * 128 : (size_t)DINNER;
  const size_t wrow_lo = (bx < 32) ? (size_t)bx * 128 : (size_t)4096;

  const int chunk0 = wave * 2, chunk1 = wave * 2 + 1;
  const int e0 = chunk0 * 512 + lane * 8;
  const int e1 = chunk1 * 512 + lane * 8;
  const int r0 = e0 >> 5, c0 = e0 & 31;
  const int r1 = e1 >> 5, c1 = e1 & 31;
  const u16* Abh = Ah + bm * (size_t)K;
  const u16* Abl = Al + bm * (size_t)K;
  const u16* Bbh = Bh + wrow_hi * (size_t)K;
  const u16* Bbl = Bl + wrow_lo * (size_t)K;

  f32x4 acc[4][4];
#pragma unroll
  for (int i = 0; i < 4; i++)
#pragma unroll
    for (int j = 0; j < 4; j++) acc[i][j] = (f32x4){0.f, 0.f, 0.f, 0.f};

  for (int k0 = 0; k0 < K; k0 += 32) {
    gload16(Abh + (size_t)r0 * K + k0 + c0, &Ash[chunk0 * 512]);
    gload16(Abh + (size_t)r1 * K + k0 + c1, &Ash[chunk1 * 512]);
    gload16(Abl + (size_t)r0 * K + k0 + c0, &Asl[chunk0 * 512]);
    gload16(Abl + (size_t)r1 * K + k0 + c1, &Asl[chunk1 * 512]);
    gload16(Bbh + (size_t)r0 * K + k0 + c0, &Bsh[chunk0 * 512]);
    gload16(Bbh + (size_t)r1 * K + k0 + c1, &Bsh[chunk1 * 512]);
    gload16(Bbl + (size_t)r0 * K + k0 + c0, &Bsl[chunk0 * 512]);
    gload16(Bbl + (size_t)r1 * K + k0 + c1, &Bsl[chunk1 * 512]);
    __syncthreads();
    const int fr = lane & 15, fk = (lane >> 4) * 8;
    bf16x8 avh[4], avl[4], bvh[4], bvl[4];
#pragma unroll
    for (int i = 0; i < 4; i++) {
      avh[i] = *(const bf16x8*)&Ash[(wm + i * 16 + fr) * 32 + fk];
      avl[i] = *(const bf16x8*)&Asl[(wm + i * 16 + fr) * 32 + fk];
    }
#pragma unroll
    for (int j = 0; j < 4; j++) {
      bvh[j] = *(const bf16x8*)&Bsh[(wn + j * 16 + fr) * 32 + fk];
      bvl[j] = *(const bf16x8*)&Bsl[(wn + j * 16 + fr) * 32 + fk];
    }
#pragma unroll
    for (int i = 0; i < 4; i++)
#pragma unroll
      for (int j = 0; j < 4; j++) {
        acc[i][j] = __builtin_amdgcn_mfma_f32_16x16x32_bf16(avh[i], bvh[j], acc[i][j], 0, 0, 0);
        acc[i][j] = __builtin_amdgcn_mfma_f32_16x16x32_bf16(avh[i], bvl[j], acc[i][j], 0, 0, 0);
        acc[i][j] = __builtin_amdgcn_mfma_f32_16x16x32_bf16(avl[i], bvh[j], acc[i][j], 0, 0, 0);
      }
    __syncthreads();
  }
  const int cr = (lane >> 4) * 4, ccol = lane & 15;
#pragma unroll
  for (int i = 0; i < 4; i++)
#pragma unroll
    for (int j = 0; j < 4; j++)
#pragma unroll
      for (int r = 0; r < 4; r++) {
        size_t row = bm + wm + i * 16 + cr + r;
        size_t col = (size_t)bx * 128 + wn + j * 16 + ccol;
        Cout[row * NXP + col] = acc[i][j][r];
      }
}

// ---------------- chunked SSM scan ----------------
// xzx: [M][NXP] f32 (x 0..4095 | B 4096..4127 | C 4128..4159 | pad). xzz: [M][4096] bf16.
__global__ __launch_bounds__(64)
void scan_pass1(const float* __restrict__ xzx, const float* __restrict__ conv_w,
                const float* __restrict__ A_log, const float* __restrict__ dt_bias,
                float* __restrict__ E) {
  const int bid = blockIdx.x;
  const int c   = bid & (NCHUNK - 1);
  const int bg  = bid >> 6;
  const int g   = bg & (GHEADS - 1);
  const int b   = bg >> 5;
  const int lane = threadIdx.x;
  const int ch0 = g * DH + lane, ch1 = ch0 + 64;

  const f32x4 w0 = ((const f32x4*)conv_w)[ch0];
  const f32x4 w1 = ((const f32x4*)conv_w)[ch1];
  const float dt = log1pf(expf(dt_bias[g]));
  const float Ac = -expf(A_log[g]);
  const float dA = expf(dt * Ac);

  const int l0 = c * SCHUNK;
  const float* base = xzx + (size_t)b * LSEQ * NXP;

  float xm3 = 0, xm2 = 0, xm1 = 0, Xm3 = 0, Xm2 = 0, Xm1 = 0;
#pragma unroll
  for (int j = 0; j < 3; j++) {
    int l = l0 - 3 + j;
    float v0 = 0, v1 = 0;
    if (l >= 0) {
      const float* rp = base + (size_t)l * NXP;
      v0 = rp[ch0]; v1 = rp[ch1];
    }
    if (j == 0) { xm3 = v0; Xm3 = v1; }
    else if (j == 1) { xm2 = v0; Xm2 = v1; }
    else { xm1 = v0; Xm1 = v1; }
  }
  float h0 = 0.f, h1 = 0.f;
  for (int t = 0; t < SCHUNK; t++) {
    const float* rp = base + (size_t)(l0 + t) * NXP;
    float xc0 = rp[ch0], xc1 = rp[ch1];
    float cx0 = w0[0] * xm3 + w0[1] * xm2 + w0[2] * xm1 + w0[3] * xc0;
    float cx1 = w1[0] * Xm3 + w1[1] * Xm2 + w1[2] * Xm1 + w1[3] * xc1;
    xm3 = xm2; xm2 = xm1; xm1 = xc0;
    Xm3 = Xm2; Xm2 = Xm1; Xm1 = xc1;
    float u = dt * rp[DGATE + g];
    h0 = dA * h0 + u * silu(cx0);
    h1 = dA * h1 + u * silu(cx1);
  }
  float* ep = E + (size_t)bid * DH;
  ep[lane] = h0; ep[lane + 64] = h1;
}

__global__ __launch_bounds__(64)
void scan_pass2(const float* __restrict__ E, float* __restrict__ Hs,
                const float* __restrict__ A_log, const float* __restrict__ dt_bias) {
  const int bg = blockIdx.x;
  const int g = bg & (GHEADS - 1);
  const int lane = threadIdx.x;
  const float dt = log1pf(expf(dt_bias[g]));
  const float Ac = -expf(A_log[g]);
  const float dAS = expf(dt * Ac * (float)SCHUNK);
  float h0 = 0.f, h1 = 0.f;
  for (int c = 0; c < NCHUNK; c++) {
    size_t idx = ((size_t)bg * NCHUNK + c) * DH;
    Hs[idx + lane] = h0; Hs[idx + lane + 64] = h1;
    h0 = dAS * h0 + E[idx + lane];
    h1 = dAS * h1 + E[idx + lane + 64];
  }
}

__global__ __launch_bounds__(64)
void scan_pass3(const float* __restrict__ xzx, const u16* __restrict__ xzz,
                const float* __restrict__ conv_w,
                const float* __restrict__ A_log, const float* __restrict__ dt_bias,
                const float* __restrict__ norm_w, const float* __restrict__ Hs,
                u16* __restrict__ gbuf) {
  const int bid = blockIdx.x;
  const int c   = bid & (NCHUNK - 1);
  const int bg  = bid >> 6;
  const int g   = bg & (GHEADS - 1);
  const int b   = bg >> 5;
  const int lane = threadIdx.x;
  const int ch0 = g * DH + lane, ch1 = ch0 + 64;

  const f32x4 wx0 = ((const f32x4*)conv_w)[ch0];
  const f32x4 wx1 = ((const f32x4*)conv_w)[ch1];
  const f32x4 wz0 = ((const f32x4*)conv_w)[DGATE + ch0];
  const f32x4 wz1 = ((const f32x4*)conv_w)[DGATE + ch1];
  const float nw0 = norm_w[lane], nw1 = norm_w[lane + 64];

  const float dt = log1pf(expf(dt_bias[g]));
  const float Ac = -expf(A_log[g]);
  const float dA = expf(dt * Ac);

  const int l0 = c * SCHUNK;
  const float* basex = xzx + (size_t)b * LSEQ * NXP;
  const u16*   basez = xzz + (size_t)b * LSEQ * DGATE;

  float xm3 = 0, xm2 = 0, xm1 = 0, Xm3 = 0, Xm2 = 0, Xm1 = 0;
  float zm3 = 0, zm2 = 0, zm1 = 0, Zm3 = 0, Zm2 = 0, Zm1 = 0;
#pragma unroll
  for (int j = 0; j < 3; j++) {
    int l = l0 - 3 + j;
    float vx0 = 0, vx1 = 0, vz0 = 0, vz1 = 0;
    if (l >= 0) {
      const float* rp = basex + (size_t)l * NXP;
      const u16*   rz = basez + (size_t)l * DGATE;
      vx0 = rp[ch0]; vx1 = rp[ch1];
      vz0 = bf2f(rz[ch0]); vz1 = bf2f(rz[ch1]);
    }
    if (j == 0) { xm3 = vx0; Xm3 = vx1; zm3 = vz0; Zm3 = vz1; }
    else if (j == 1) { xm2 = vx0; Xm2 = vx1; zm2 = vz0; Zm2 = vz1; }
    else { xm1 = vx0; Xm1 = vx1; zm1 = vz0; Zm1 = vz1; }
  }
  float h0 = Hs[(size_t)bid * DH + lane];
  float h1 = Hs[(size_t)bid * DH + lane + 64];
  for (int t = 0; t < SCHUNK; t++) {
    const int l = l0 + t;
    const float* rp = basex + (size_t)l * NXP;
    const u16*   rz = basez + (size_t)l * DGATE;
    float xc0 = rp[ch0], xc1 = rp[ch1];
    float zc0 = bf2f(rz[ch0]), zc1 = bf2f(rz[ch1]);
    float cx0 = wx0[0] * xm3 + wx0[1] * xm2 + wx0[2] * xm1 + wx0[3] * xc0;
    float cx1 = wx1[0] * Xm3 + wx1[1] * Xm2 + wx1[2] * Xm1 + wx1[3] * xc1;
    float cz0 = wz0[0] * zm3 + wz0[1] * zm2 + wz0[2] * zm1 + wz0[3] * zc0;
    float cz1 = wz1[0] * Zm3 + wz1[1] * Zm2 + wz1[2] * Zm1 + wz1[3] * zc1;
    xm3 = xm2; xm2 = xm1; xm1 = xc0;  Xm3 = Xm2; Xm2 = Xm1; Xm1 = xc1;
    zm3 = zm2; zm2 = zm1; zm1 = zc0;  Zm3 = Zm2; Zm2 = Zm1; Zm1 = zc1;
    float bcl = rp[DGATE + g];
    float ccl = rp[DGATE + 32 + g];
    float u = dt * bcl;
    h0 = dA * h0 + u * silu(cx0);
    h1 = dA * h1 + u * silu(cx1);
    float y0 = ccl * h0, y1 = ccl * h1;
    float ss = y0 * y0 + y1 * y1;
    ss += __shfl_xor(ss, 32); ss += __shfl_xor(ss, 16); ss += __shfl_xor(ss, 8);
    ss += __shfl_xor(ss, 4);  ss += __shfl_xor(ss, 2);  ss += __shfl_xor(ss, 1);
    const float sc = rsqrtf(ss * (1.0f / DH) + 1e-6f);
    u16* op = gbuf + (size_t)(b * LSEQ + l) * DGATE + g * DH;
    op[lane]      = f2bf(y0 * sc * nw0 * silu(cz0));
    op[lane + 64] = f2bf(y1 * sc * nw1 * silu(cz1));
  }
}

// ---------------- launch ----------------
extern "C" void kernel_launch(void* const* d_in, const int* in_sizes, int n_in,
                              void* d_out, int out_size, void* d_ws, size_t ws_size,
                              hipStream_t stream) {
  (void)in_sizes; (void)n_in; (void)out_size; (void)ws_size;
  const float* hs    = (const float*)d_in[0];
  const float* Wqkv  = (const float*)d_in[1];
  const float* Wb    = (const float*)d_in[2];
  const float* Wa    = (const float*)d_in[3];
  const float* convw = (const float*)d_in[4];
  const float* Wout  = (const float*)d_in[5];
  const float* normw = (const float*)d_in[6];
  const float* Alog  = (const float*)d_in[7];
  const float* dtb   = (const float*)d_in[8];
  float* out = (float*)d_out;

  // ws layout (299 MB; round-3-proven):
  // [xzx 138.4 | xzz 67.1 | wc_hi 42.6 | wc_lo 21.6 | pad 4.2 | wout 21.0 | E 2.1 | Hst 2.1]
  char* ws = (char*)d_ws;
  size_t off = 0;
  auto alloc = [&](size_t bytes) { void* p = ws + off; off += (bytes + 255) & ~(size_t)255; return p; };
  float* xzx    = (float*)alloc((size_t)MROWS * NXP * 4);        // 138.4 MB
  u16*   xzz    = (u16*)alloc((size_t)MROWS * DGATE * 2);        // 67.1 MB
  u16*   wc_hi  = (u16*)alloc((size_t)8320 * H_DIM * 2);         // 42.6 MB
  u16*   wc_lo  = (u16*)alloc((size_t)4224 * H_DIM * 2);         // 21.6 MB
  (void)alloc((size_t)4 << 20);                                  // 4.2 MB pad (gbuf tail)
  u16*   wout_bf= (u16*)alloc((size_t)H_DIM * DGATE * 2);        // 21.0 MB
  float* E      = (float*)alloc((size_t)BSZ * GHEADS * NCHUNK * DH * 4);
  float* Hst    = (float*)alloc((size_t)BSZ * GHEADS * NCHUNK * DH * 4);
  // gbuf (67.1 MB) aliases [wc_hi | wc_lo | pad] (68.4 MB): wc_* dead after GEMM1a/b,
  // pass3 (writer) launches strictly after them.
  u16*   gbuf   = wc_hi;
  // hs_hi|hs_lo (2 x 41.94 MB) live in d_out (83.89 MB), dead until GEMM2 overwrites it.
  u16*   hs_hi  = (u16*)d_out;
  u16*   hs_lo  = hs_hi + (size_t)MROWS * H_DIM;

  const int n4_hs = MROWS * H_DIM / 4;
  cast_split<<<(n4_hs + 255) / 256, 256, 0, stream>>>(hs, hs_hi, hs_lo, n4_hs);
  build_wc_split<<<8320, 256, 0, stream>>>(Wqkv, Wb, Wa, wc_hi, wc_lo);
  const int n4_wo = H_DIM * DGATE / 4;
  cast_f32_bf16<<<(n4_wo + 255) / 256, 256, 0, stream>>>(Wout, wout_bf, n4_wo);

  // GEMM1a (precise, 3-product, all-gload staging): x|B|C -> f32 [8192, 4224]
  gemm_precise<<<dim3(33, MROWS / 128), 256, 0, stream>>>(hs_hi, hs_lo, wc_hi, wc_lo, xzx);
  // GEMM1b (plain): z -> bf16 [8192, 4096]
  gemm_bt128<true><<<dim3(32, MROWS / 128), 256, 0, stream>>>(
      hs_hi, wc_hi + (size_t)DGATE * H_DIM, xzz, H_DIM, DGATE);

  scan_pass1<<<BSZ * GHEADS * NCHUNK, 64, 0, stream>>>(xzx, convw, Alog, dtb, E);
  scan_pass2<<<BSZ * GHEADS, 64, 0, stream>>>(E, Hst, Alog, dtb);
  scan_pass3<<<BSZ * GHEADS * NCHUNK, 64, 0, stream>>>(xzx, xzz, convw, Alog, dtb, normw, Hst, gbuf);

  // GEMM2: out = gated @ W_out^T -> f32 [8192, 2560] (overwrites hs_hi/hs_lo scratch)
  gemm_bt128<false><<<dim3(H_DIM / 128, MROWS / 128), 256, 0, stream>>>(gbuf, wout_bf, out, DGATE, H_DIM);
}

// Round 5
// 1448.929 us; speedup vs baseline: 1.0809x; 1.0809x over previous
//
#include <hip/hip_runtime.h>
#include <cstdint>
#include <cstddef>

// ---------------- problem geometry ----------------
#define H_DIM   2560
#define DINNER  8192
#define GHEADS  32
#define DGATE   4096
#define DH      128
#define BSZ     2
#define LSEQ    4096
#define MROWS   (BSZ*LSEQ)     // 8192 token rows
#define NXPAD   4352           // precise out width: 4096 x | 32 B | 32 C | 192 pad (=17*256)
#define NCHUNK  64
#define SCHUNK  (LSEQ/NCHUNK)  // 64

typedef __attribute__((ext_vector_type(4))) float  f32x4;
typedef __attribute__((ext_vector_type(8))) __bf16 bf16x8;
typedef unsigned short u16;
typedef unsigned int   u32;

static __device__ __forceinline__ u16 f2bf(float f) {
  union { float f; u32 u; } v; v.f = f;
  u32 r = v.u + 0x7fffu + ((v.u >> 16) & 1u);   // RNE
  return (u16)(r >> 16);
}
static __device__ __forceinline__ float bf2f(u16 u) {
  union { u32 u; float f; } v; v.u = ((u32)u) << 16;
  return v.f;
}
static __device__ __forceinline__ float silu(float x) {
  return x / (1.0f + expf(-x));
}

// ---------------- prep casts ----------------
__global__ void cast_f32_bf16(const float* __restrict__ in, u16* __restrict__ out, int n4) {
  int i = blockIdx.x * blockDim.x + threadIdx.x;
  if (i < n4) {
    f32x4 v = ((const f32x4*)in)[i];
    u32 p0 = (u32)f2bf(v[0]) | ((u32)f2bf(v[1]) << 16);
    u32 p1 = (u32)f2bf(v[2]) | ((u32)f2bf(v[3]) << 16);
    ((uint2*)out)[i] = make_uint2(p0, p1);
  }
}

// split f32 -> hi bf16 + lo bf16 (lo = RNE(x - hi))
__global__ void cast_split(const float* __restrict__ in, u16* __restrict__ hi,
                           u16* __restrict__ lo, int n4) {
  int i = blockIdx.x * blockDim.x + threadIdx.x;
  if (i < n4) {
    f32x4 v = ((const f32x4*)in)[i];
    u16 h[4], l[4];
#pragma unroll
    for (int j = 0; j < 4; j++) {
      h[j] = f2bf(v[j]);
      l[j] = f2bf(v[j] - bf2f(h[j]));
    }
    ((uint2*)hi)[i] = make_uint2((u32)h[0] | ((u32)h[1] << 16), (u32)h[2] | ((u32)h[3] << 16));
    ((uint2*)lo)[i] = make_uint2((u32)l[0] | ((u32)l[1] << 16), (u32)l[2] | ((u32)l[3] << 16));
  }
}

// wcp_hi/lo rows (4352): 0..4095 = Wqkv x-rows, 4096..4127 = Wb, 4128..4159 = Wa, 4160..4351 = 0
// wz rows (4096): hi(Wqkv z-rows 4096..8191)
__global__ void build_wc(const float* __restrict__ Wqkv, const float* __restrict__ Wb,
                         const float* __restrict__ Wa, u16* __restrict__ wcp_hi,
                         u16* __restrict__ wcp_lo, u16* __restrict__ wz) {
  int row = blockIdx.x;              // 0..8447
  if (row >= NXPAD) {
    // z rows, hi only
    const float* src = Wqkv + (size_t)(4096 + row - NXPAD) * H_DIM;
    u16* oh = wz + (size_t)(row - NXPAD) * H_DIM;
    for (int i = threadIdx.x; i < H_DIM / 4; i += blockDim.x) {
      f32x4 v = ((const f32x4*)src)[i];
      u16 h[4];
#pragma unroll
      for (int j = 0; j < 4; j++) h[j] = f2bf(v[j]);
      ((uint2*)oh)[i] = make_uint2((u32)h[0] | ((u32)h[1] << 16), (u32)h[2] | ((u32)h[3] << 16));
    }
    return;
  }
  const float* src = nullptr;
  if (row < 4096)              src = Wqkv + (size_t)row * H_DIM;
  else if (row < 4128)         src = Wb + (size_t)(row - 4096) * H_DIM;
  else if (row < 4160)         src = Wa + (size_t)(row - 4128) * H_DIM;
  u16* oh = wcp_hi + (size_t)row * H_DIM;
  u16* ol = wcp_lo + (size_t)row * H_DIM;
  for (int i = threadIdx.x; i < H_DIM / 4; i += blockDim.x) {
    u16 h[4] = {0, 0, 0, 0}, l[4] = {0, 0, 0, 0};
    if (src) {
      f32x4 v = ((const f32x4*)src)[i];
#pragma unroll
      for (int j = 0; j < 4; j++) {
        h[j] = f2bf(v[j]);
        l[j] = f2bf(v[j] - bf2f(h[j]));
      }
    }
    ((uint2*)oh)[i] = make_uint2((u32)h[0] | ((u32)h[1] << 16), (u32)h[2] | ((u32)h[3] << 16));
    ((uint2*)ol)[i] = make_uint2((u32)l[0] | ((u32)l[1] << 16), (u32)l[2] | ((u32)l[3] << 16));
  }
}

// ---------------- GEMM helpers ----------------
static __device__ __forceinline__ void gload16(const u16* g, u16* l) {
  __builtin_amdgcn_global_load_lds(
      (const __attribute__((address_space(1))) u32*)g,
      (__attribute__((address_space(3))) u32*)l, 16, 0, 0);
}

// plain 1-product GEMM with XCD-grouped swizzle. 1-D grid nbx*64 blocks, 256 thr.
// lsw=(bid&7)*cpx+(bid>>3); by=lsw/nbx (XCD-contiguous stripes), bx=lsw%nbx.
template<bool OUT_BF16>
__global__ __launch_bounds__(256)
void gemm_bt128(const u16* __restrict__ A, const u16* __restrict__ Bt,
                void* __restrict__ Cout, int K, int ldc, int nbx, int cpx) {
  __shared__ __align__(16) u16 As[128 * 32];
  __shared__ __align__(16) u16 Bs[128 * 32];
  const int tid  = threadIdx.x;
  const int lane = tid & 63;
  const int wave = tid >> 6;
  const int wm = (wave & 1) * 64;
  const int wn = (wave >> 1) * 64;
  const int bid = blockIdx.x;
  const int lsw = (bid & 7) * cpx + (bid >> 3);
  const int by  = lsw / nbx;
  const int bx  = lsw - by * nbx;
  const size_t bm = (size_t)by * 128;
  const size_t bn = (size_t)bx * 128;

  const int e0 = (wave * 2) * 512 + lane * 8;
  const int e1 = (wave * 2 + 1) * 512 + lane * 8;
  const int r0 = e0 >> 5, c0 = e0 & 31;
  const int r1 = e1 >> 5, c1 = e1 & 31;
  const u16* Ab = A + bm * (size_t)K;
  const u16* Bb = Bt + bn * (size_t)K;

  f32x4 acc[4][4];
#pragma unroll
  for (int i = 0; i < 4; i++)
#pragma unroll
    for (int j = 0; j < 4; j++) acc[i][j] = (f32x4){0.f, 0.f, 0.f, 0.f};

  for (int k0 = 0; k0 < K; k0 += 32) {
    gload16(Ab + (size_t)r0 * K + k0 + c0, &As[(wave * 2) * 512]);
    gload16(Ab + (size_t)r1 * K + k0 + c1, &As[(wave * 2 + 1) * 512]);
    gload16(Bb + (size_t)r0 * K + k0 + c0, &Bs[(wave * 2) * 512]);
    gload16(Bb + (size_t)r1 * K + k0 + c1, &Bs[(wave * 2 + 1) * 512]);
    __syncthreads();
    const int fr = lane & 15, fk = (lane >> 4) * 8;
    bf16x8 av[4], bv[4];
#pragma unroll
    for (int i = 0; i < 4; i++) av[i] = *(const bf16x8*)&As[(wm + i * 16 + fr) * 32 + fk];
#pragma unroll
    for (int j = 0; j < 4; j++) bv[j] = *(const bf16x8*)&Bs[(wn + j * 16 + fr) * 32 + fk];
#pragma unroll
    for (int i = 0; i < 4; i++)
#pragma unroll
      for (int j = 0; j < 4; j++)
        acc[i][j] = __builtin_amdgcn_mfma_f32_16x16x32_bf16(av[i], bv[j], acc[i][j], 0, 0, 0);
    __syncthreads();
  }
  const int cr = (lane >> 4) * 4, ccol = lane & 15;
#pragma unroll
  for (int i = 0; i < 4; i++)
#pragma unroll
    for (int j = 0; j < 4; j++)
#pragma unroll
      for (int r = 0; r < 4; r++) {
        size_t row = bm + wm + i * 16 + cr + r;
        size_t col = bn + wn + j * 16 + ccol;
        if (OUT_BF16) ((u16*)Cout)[row * ldc + col] = f2bf(acc[i][j][r]);
        else          ((float*)Cout)[row * ldc + col] = acc[i][j][r];
      }
}

// precise 3-product GEMM: acc += Ah*Bh + Ah*Bl + Al*Bh; f32 out [8192, 4352].
// 128M x 256N tile, 512 thr (8 waves, 2x4), per-wave 64x64 (4x4 frags).
// 1-D grid 1088 blocks, XCD-grouped swizzle (cpx=136, nbx=17).
__global__ __launch_bounds__(512)
void gemm_precise(const u16* __restrict__ Ah, const u16* __restrict__ Al,
                  const u16* __restrict__ Bh, const u16* __restrict__ Bl,
                  float* __restrict__ Cout) {
  __shared__ __align__(16) u16 Ash[128 * 32];
  __shared__ __align__(16) u16 Asl[128 * 32];
  __shared__ __align__(16) u16 Bsh[256 * 32];
  __shared__ __align__(16) u16 Bsl[256 * 32];
  const int K = H_DIM;
  const int tid  = threadIdx.x;
  const int lane = tid & 63;
  const int wave = tid >> 6;          // 0..7
  const int wm = (wave & 1) * 64;     // 0,64
  const int wn = (wave >> 1) * 64;    // 0,64,128,192
  const int bid = blockIdx.x;         // 0..1087
  const int lsw = (bid & 7) * 136 + (bid >> 3);
  const int by  = lsw / 17;
  const int bx  = lsw - by * 17;
  const size_t bm = (size_t)by * 128;

  // A staging: 128x32 elems, 8 waves x 512; lane covers eA = wave*512 + lane*8
  const int eA = wave * 512 + lane * 8;
  const int rA = eA >> 5, cA = eA & 31;
  // B staging: 256x32 elems, wave covers [wave*1024, wave*1024+1024)
  const int eB0 = wave * 1024 + lane * 8, eB1 = eB0 + 512;
  const int rB0 = eB0 >> 5, cB0 = eB0 & 31;
  const int rB1 = eB1 >> 5, cB1 = eB1 & 31;

  const u16* Abh = Ah + bm * (size_t)K;
  const u16* Abl = Al + bm * (size_t)K;
  const u16* Bbh = Bh + (size_t)bx * 256 * K;
  const u16* Bbl = Bl + (size_t)bx * 256 * K;

  f32x4 acc[4][4];
#pragma unroll
  for (int i = 0; i < 4; i++)
#pragma unroll
    for (int j = 0; j < 4; j++) acc[i][j] = (f32x4){0.f, 0.f, 0.f, 0.f};

  for (int k0 = 0; k0 < K; k0 += 32) {
    gload16(Abh + (size_t)rA * K + k0 + cA, &Ash[wave * 512]);
    gload16(Abl + (size_t)rA * K + k0 + cA, &Asl[wave * 512]);
    gload16(Bbh + (size_t)rB0 * K + k0 + cB0, &Bsh[wave * 1024]);
    gload16(Bbh + (size_t)rB1 * K + k0 + cB1, &Bsh[wave * 1024 + 512]);
    gload16(Bbl + (size_t)rB0 * K + k0 + cB0, &Bsl[wave * 1024]);
    gload16(Bbl + (size_t)rB1 * K + k0 + cB1, &Bsl[wave * 1024 + 512]);
    __syncthreads();
    const int fr = lane & 15, fk = (lane >> 4) * 8;
    bf16x8 avh[4], avl[4], bvh[4], bvl[4];
#pragma unroll
    for (int i = 0; i < 4; i++) {
      avh[i] = *(const bf16x8*)&Ash[(wm + i * 16 + fr) * 32 + fk];
      avl[i] = *(const bf16x8*)&Asl[(wm + i * 16 + fr) * 32 + fk];
    }
#pragma unroll
    for (int j = 0; j < 4; j++) {
      bvh[j] = *(const bf16x8*)&Bsh[(wn + j * 16 + fr) * 32 + fk];
      bvl[j] = *(const bf16x8*)&Bsl[(wn + j * 16 + fr) * 32 + fk];
    }
#pragma unroll
    for (int i = 0; i < 4; i++)
#pragma unroll
      for (int j = 0; j < 4; j++) {
        acc[i][j] = __builtin_amdgcn_mfma_f32_16x16x32_bf16(avh[i], bvh[j], acc[i][j], 0, 0, 0);
        acc[i][j] = __builtin_amdgcn_mfma_f32_16x16x32_bf16(avh[i], bvl[j], acc[i][j], 0, 0, 0);
        acc[i][j] = __builtin_amdgcn_mfma_f32_16x16x32_bf16(avl[i], bvh[j], acc[i][j], 0, 0, 0);
      }
    __syncthreads();
  }
  const int cr = (lane >> 4) * 4, ccol = lane & 15;
#pragma unroll
  for (int i = 0; i < 4; i++)
#pragma unroll
    for (int j = 0; j < 4; j++)
#pragma unroll
      for (int r = 0; r < 4; r++) {
        size_t row = bm + wm + i * 16 + cr + r;
        size_t col = (size_t)bx * 256 + wn + j * 16 + ccol;
        Cout[row * NXPAD + col] = acc[i][j][r];
      }
}

// ---------------- chunked SSM scan ----------------
// xzx: [M][NXPAD] f32 (x 0..4095 | B 4096..4127 | C 4128..4159 | pad). xzz: [M][4096] bf16.
__global__ __launch_bounds__(64)
void scan_pass1(const float* __restrict__ xzx, const float* __restrict__ conv_w,
                const float* __restrict__ A_log, const float* __restrict__ dt_bias,
                float* __restrict__ E) {
  const int bid = blockIdx.x;
  const int c   = bid & (NCHUNK - 1);
  const int bg  = bid >> 6;
  const int g   = bg & (GHEADS - 1);
  const int b   = bg >> 5;
  const int lane = threadIdx.x;
  const int ch0 = g * DH + lane, ch1 = ch0 + 64;

  const f32x4 w0 = ((const f32x4*)conv_w)[ch0];
  const f32x4 w1 = ((const f32x4*)conv_w)[ch1];
  const float dt = log1pf(expf(dt_bias[g]));
  const float Ac = -expf(A_log[g]);
  const float dA = expf(dt * Ac);

  const int l0 = c * SCHUNK;
  const float* base = xzx + (size_t)b * LSEQ * NXPAD;

  float xm3 = 0, xm2 = 0, xm1 = 0, Xm3 = 0, Xm2 = 0, Xm1 = 0;
#pragma unroll
  for (int j = 0; j < 3; j++) {
    int l = l0 - 3 + j;
    float v0 = 0, v1 = 0;
    if (l >= 0) {
      const float* rp = base + (size_t)l * NXPAD;
      v0 = rp[ch0]; v1 = rp[ch1];
    }
    if (j == 0) { xm3 = v0; Xm3 = v1; }
    else if (j == 1) { xm2 = v0; Xm2 = v1; }
    else { xm1 = v0; Xm1 = v1; }
  }
  float h0 = 0.f, h1 = 0.f;
  for (int t = 0; t < SCHUNK; t++) {
    const float* rp = base + (size_t)(l0 + t) * NXPAD;
    float xc0 = rp[ch0], xc1 = rp[ch1];
    float cx0 = w0[0] * xm3 + w0[1] * xm2 + w0[2] * xm1 + w0[3] * xc0;
    float cx1 = w1[0] * Xm3 + w1[1] * Xm2 + w1[2] * Xm1 + w1[3] * xc1;
    xm3 = xm2; xm2 = xm1; xm1 = xc0;
    Xm3 = Xm2; Xm2 = Xm1; Xm1 = xc1;
    float u = dt * rp[DGATE + g];
    h0 = dA * h0 + u * silu(cx0);
    h1 = dA * h1 + u * silu(cx1);
  }
  float* ep = E + (size_t)bid * DH;
  ep[lane] = h0; ep[lane + 64] = h1;
}

__global__ __launch_bounds__(64)
void scan_pass2(const float* __restrict__ E, float* __restrict__ Hs,
                const float* __restrict__ A_log, const float* __restrict__ dt_bias) {
  const int bg = blockIdx.x;
  const int g = bg & (GHEADS - 1);
  const int lane = threadIdx.x;
  const float dt = log1pf(expf(dt_bias[g]));
  const float Ac = -expf(A_log[g]);
  const float dAS = expf(dt * Ac * (float)SCHUNK);
  float h0 = 0.f, h1 = 0.f;
  for (int c = 0; c < NCHUNK; c++) {
    size_t idx = ((size_t)bg * NCHUNK + c) * DH;
    Hs[idx + lane] = h0; Hs[idx + lane + 64] = h1;
    h0 = dAS * h0 + E[idx + lane];
    h1 = dAS * h1 + E[idx + lane + 64];
  }
}

__global__ __launch_bounds__(64)
void scan_pass3(const float* __restrict__ xzx, const u16* __restrict__ xzz,
                const float* __restrict__ conv_w,
                const float* __restrict__ A_log, const float* __restrict__ dt_bias,
                const float* __restrict__ norm_w, const float* __restrict__ Hs,
                u16* __restrict__ gbuf) {
  const int bid = blockIdx.x;
  const int c   = bid & (NCHUNK - 1);
  const int bg  = bid >> 6;
  const int g   = bg & (GHEADS - 1);
  const int b   = bg >> 5;
  const int lane = threadIdx.x;
  const int ch0 = g * DH + lane, ch1 = ch0 + 64;

  const f32x4 wx0 = ((const f32x4*)conv_w)[ch0];
  const f32x4 wx1 = ((const f32x4*)conv_w)[ch1];
  const f32x4 wz0 = ((const f32x4*)conv_w)[DGATE + ch0];
  const f32x4 wz1 = ((const f32x4*)conv_w)[DGATE + ch1];
  const float nw0 = norm_w[lane], nw1 = norm_w[lane + 64];

  const float dt = log1pf(expf(dt_bias[g]));
  const float Ac = -expf(A_log[g]);
  const float dA = expf(dt * Ac);

  const int l0 = c * SCHUNK;
  const float* basex = xzx + (size_t)b * LSEQ * NXPAD;
  const u16*   basez = xzz + (size_t)b * LSEQ * DGATE;

  float xm3 = 0, xm2 = 0, xm1 = 0, Xm3 = 0, Xm2 = 0, Xm1 = 0;
  float zm3 = 0, zm2 = 0, zm1 = 0, Zm3 = 0, Zm2 = 0, Zm1 = 0;
#pragma unroll
  for (int j = 0; j < 3; j++) {
    int l = l0 - 3 + j;
    float vx0 = 0, vx1 = 0, vz0 = 0, vz1 = 0;
    if (l >= 0) {
      const float* rp = basex + (size_t)l * NXPAD;
      const u16*   rz = basez + (size_t)l * DGATE;
      vx0 = rp[ch0]; vx1 = rp[ch1];
      vz0 = bf2f(rz[ch0]); vz1 = bf2f(rz[ch1]);
    }
    if (j == 0) { xm3 = vx0; Xm3 = vx1; zm3 = vz0; Zm3 = vz1; }
    else if (j == 1) { xm2 = vx0; Xm2 = vx1; zm2 = vz0; Zm2 = vz1; }
    else { xm1 = vx0; Xm1 = vx1; zm1 = vz0; Zm1 = vz1; }
  }
  float h0 = Hs[(size_t)bid * DH + lane];
  float h1 = Hs[(size_t)bid * DH + lane + 64];
  for (int t = 0; t < SCHUNK; t++) {
    const int l = l0 + t;
    const float* rp = basex + (size_t)l * NXPAD;
    const u16*   rz = basez + (size_t)l * DGATE;
    float xc0 = rp[ch0], xc1 = rp[ch1];
    float zc0 = bf2f(rz[ch0]), zc1 = bf2f(rz[ch1]);
    float cx0 = wx0[0] * xm3 + wx0[1] * xm2 + wx0[2] * xm1 + wx0[3] * xc0;
    float cx1 = wx1[0] * Xm3 + wx1[1] * Xm2 + wx1[2] * Xm1 + wx1[3] * xc1;
    float cz0 = wz0[0] * zm3 + wz0[1] * zm2 + wz0[2] * zm1 + wz0[3] * zc0;
    float cz1 = wz1[0] * Zm3 + wz1[1] * Zm2 + wz1[2] * Zm1 + wz1[3] * zc1;
    xm3 = xm2; xm2 = xm1; xm1 = xc0;  Xm3 = Xm2; Xm2 = Xm1; Xm1 = xc1;
    zm3 = zm2; zm2 = zm1; zm1 = zc0;  Zm3 = Zm2; Zm2 = Zm1; Zm1 = zc1;
    float bcl = rp[DGATE + g];
    float ccl = rp[DGATE + 32 + g];
    float u = dt * bcl;
    h0 = dA * h0 + u * silu(cx0);
    h1 = dA * h1 + u * silu(cx1);
    float y0 = ccl * h0, y1 = ccl * h1;
    float ss = y0 * y0 + y1 * y1;
    ss += __shfl_xor(ss, 32); ss += __shfl_xor(ss, 16); ss += __shfl_xor(ss, 8);
    ss += __shfl_xor(ss, 4);  ss += __shfl_xor(ss, 2);  ss += __shfl_xor(ss, 1);
    const float sc = rsqrtf(ss * (1.0f / DH) + 1e-6f);
    u16* op = gbuf + (size_t)(b * LSEQ + l) * DGATE + g * DH;
    op[lane]      = f2bf(y0 * sc * nw0 * silu(cz0));
    op[lane + 64] = f2bf(y1 * sc * nw1 * silu(cz1));
  }
}

// ---------------- launch ----------------
extern "C" void kernel_launch(void* const* d_in, const int* in_sizes, int n_in,
                              void* d_out, int out_size, void* d_ws, size_t ws_size,
                              hipStream_t stream) {
  (void)in_sizes; (void)n_in; (void)out_size; (void)ws_size;
  const float* hs    = (const float*)d_in[0];
  const float* Wqkv  = (const float*)d_in[1];
  const float* Wb    = (const float*)d_in[2];
  const float* Wa    = (const float*)d_in[3];
  const float* convw = (const float*)d_in[4];
  const float* Wout  = (const float*)d_in[5];
  const float* normw = (const float*)d_in[6];
  const float* Alog  = (const float*)d_in[7];
  const float* dtb   = (const float*)d_in[8];
  float* out = (float*)d_out;

  // ws layout (302.5 MB; <= 313 proven-safe):
  // [xzx 142.6 | xzz 67.1 | wcp_hi 22.3 | wcp_lo 22.3 | wz 21.0 | pad 2.1 | wout 21.0 | E 2.1 | Hst 2.1]
  char* ws = (char*)d_ws;
  size_t off = 0;
  auto alloc = [&](size_t bytes) { void* p = ws + off; off += (bytes + 255) & ~(size_t)255; return p; };
  float* xzx    = (float*)alloc((size_t)MROWS * NXPAD * 4);      // 142.6 MB
  u16*   xzz    = (u16*)alloc((size_t)MROWS * DGATE * 2);        // 67.1 MB
  u16*   wcp_hi = (u16*)alloc((size_t)NXPAD * H_DIM * 2);        // 22.3 MB
  u16*   wcp_lo = (u16*)alloc((size_t)NXPAD * H_DIM * 2);        // 22.3 MB
  u16*   wz     = (u16*)alloc((size_t)DGATE * H_DIM * 2);        // 21.0 MB
  (void)alloc((size_t)2 << 20);                                  // 2.1 MB pad (gbuf tail)
  u16*   wout_bf= (u16*)alloc((size_t)H_DIM * DGATE * 2);        // 21.0 MB
  float* E      = (float*)alloc((size_t)BSZ * GHEADS * NCHUNK * DH * 4);
  float* Hst    = (float*)alloc((size_t)BSZ * GHEADS * NCHUNK * DH * 4);
  // gbuf (67.1 MB) aliases [wcp_hi|wcp_lo|wz|pad] (67.6 MB): those are dead after the
  // two GEMM1s; pass3 (writer) launches strictly after them. Never touches wout.
  u16*   gbuf   = wcp_hi;
  // hs_hi|hs_lo (2 x 41.94 MB) live in d_out (83.89 MB), dead until GEMM2 overwrites it.
  u16*   hs_hi  = (u16*)d_out;
  u16*   hs_lo  = hs_hi + (size_t)MROWS * H_DIM;

  const int n4_hs = MROWS * H_DIM / 4;
  cast_split<<<(n4_hs + 255) / 256, 256, 0, stream>>>(hs, hs_hi, hs_lo, n4_hs);
  build_wc<<<NXPAD + DGATE, 256, 0, stream>>>(Wqkv, Wb, Wa, wcp_hi, wcp_lo, wz);
  const int n4_wo = H_DIM * DGATE / 4;
  cast_f32_bf16<<<(n4_wo + 255) / 256, 256, 0, stream>>>(Wout, wout_bf, n4_wo);

  // GEMM1a (precise, 3-product, 128x256 tile): x|B|C -> f32 [8192, 4352]
  gemm_precise<<<1088, 512, 0, stream>>>(hs_hi, hs_lo, wcp_hi, wcp_lo, xzx);
  // GEMM1b (plain): z -> bf16 [8192, 4096].  grid 32x64 -> 2048, cpx=256
  gemm_bt128<true><<<2048, 256, 0, stream>>>(hs_hi, wz, xzz, H_DIM, DGATE, 32, 256);

  scan_pass1<<<BSZ * GHEADS * NCHUNK, 64, 0, stream>>>(xzx, convw, Alog, dtb, E);
  scan_pass2<<<BSZ * GHEADS, 64, 0, stream>>>(E, Hst, Alog, dtb);
  scan_pass3<<<BSZ * GHEADS * NCHUNK, 64, 0, stream>>>(xzx, xzz, convw, Alog, dtb, normw, Hst, gbuf);

  // GEMM2: out = gated @ W_out^T -> f32 [8192, 2560].  grid 20x64 -> 1280, cpx=160
  gemm_bt128<false><<<1280, 256, 0, stream>>>(gbuf, wout_bf, out, DGATE, H_DIM, 20, 160);
}

// Round 6
// 860.396 us; speedup vs baseline: 1.8203x; 1.6840x over previous
//
#include <hip/hip_runtime.h>
#include <cstdint>
#include <cstddef>

// ---------------- problem geometry ----------------
#define H_DIM   2560
#define DINNER  8192
#define GHEADS  32
#define DGATE   4096
#define DH      128
#define BSZ     2
#define LSEQ    4096
#define MROWS   (BSZ*LSEQ)     // 8192 token rows
#define NXPAD   4352           // precise out width: 4096 x | 32 B | 32 C | 192 pad (=17*256)
#define NCHUNK  64
#define SCHUNK  (LSEQ/NCHUNK)  // 64

typedef __attribute__((ext_vector_type(4))) float    f32x4;
typedef __attribute__((ext_vector_type(8))) _Float16 f16x8;
typedef unsigned short u16;
typedef unsigned int   u32;

static __device__ __forceinline__ u16 f2h(float f) {
  _Float16 h = (_Float16)f;          // v_cvt_f16_f32, RNE
  union { _Float16 h; u16 u; } v; v.h = h; return v.u;
}
static __device__ __forceinline__ float h2f(u16 u) {
  union { u16 u; _Float16 h; } v; v.u = u; return (float)v.h;
}
static __device__ __forceinline__ float silu(float x) {
  return x / (1.0f + expf(-x));
}

// ---------------- prep casts (f32 -> fp16) ----------------
__global__ void cast_f32_f16(const float* __restrict__ in, u16* __restrict__ out, int n4) {
  int i = blockIdx.x * blockDim.x + threadIdx.x;
  if (i < n4) {
    f32x4 v = ((const f32x4*)in)[i];
    u32 p0 = (u32)f2h(v[0]) | ((u32)f2h(v[1]) << 16);
    u32 p1 = (u32)f2h(v[2]) | ((u32)f2h(v[3]) << 16);
    ((uint2*)out)[i] = make_uint2(p0, p1);
  }
}

// wcp rows (4352): 0..4095 = Wqkv x-rows, 4096..4127 = Wb, 4128..4159 = Wa, 4160..4351 = 0
// wz rows (4096): Wqkv z-rows 4096..8191
__global__ void build_wc(const float* __restrict__ Wqkv, const float* __restrict__ Wb,
                         const float* __restrict__ Wa, u16* __restrict__ wcp,
                         u16* __restrict__ wz) {
  int row = blockIdx.x;              // 0..8447
  if (row >= NXPAD) {
    const float* src = Wqkv + (size_t)(4096 + row - NXPAD) * H_DIM;
    u16* oh = wz + (size_t)(row - NXPAD) * H_DIM;
    for (int i = threadIdx.x; i < H_DIM / 4; i += blockDim.x) {
      f32x4 v = ((const f32x4*)src)[i];
      ((uint2*)oh)[i] = make_uint2((u32)f2h(v[0]) | ((u32)f2h(v[1]) << 16),
                                   (u32)f2h(v[2]) | ((u32)f2h(v[3]) << 16));
    }
    return;
  }
  const float* src = nullptr;
  if (row < 4096)              src = Wqkv + (size_t)row * H_DIM;
  else if (row < 4128)         src = Wb + (size_t)(row - 4096) * H_DIM;
  else if (row < 4160)         src = Wa + (size_t)(row - 4128) * H_DIM;
  u16* oh = wcp + (size_t)row * H_DIM;
  for (int i = threadIdx.x; i < H_DIM / 4; i += blockDim.x) {
    u32 p0 = 0, p1 = 0;
    if (src) {
      f32x4 v = ((const f32x4*)src)[i];
      p0 = (u32)f2h(v[0]) | ((u32)f2h(v[1]) << 16);
      p1 = (u32)f2h(v[2]) | ((u32)f2h(v[3]) << 16);
    }
    ((uint2*)oh)[i] = make_uint2(p0, p1);
  }
}

// ---------------- GEMM ----------------
static __device__ __forceinline__ void gload16(const u16* g, u16* l) {
  __builtin_amdgcn_global_load_lds(
      (const __attribute__((address_space(1))) u32*)g,
      (__attribute__((address_space(3))) u32*)l, 16, 0, 0);
}

// Unified fp16 GEMM: C[m,n] = sum_k A[m,k]*Bt[n,k]. 128M x 256N tile, 512 thr
// (8 waves 2x4, per-wave 64x64, 4x4 16x16x32 frags). Double-buffered LDS:
// STAGE(next) issued before COMPUTE(cur); one __syncthreads (vmcnt drain) per
// K-step AFTER the MFMA phase -> load latency hides under compute. K % 64 == 0.
// 1-D grid nbx*(M/128) blocks, XCD-grouped swizzle (cpx = grid/8).
template<bool OUT_F16>
__global__ __launch_bounds__(512)
void gemm_h(const u16* __restrict__ A, const u16* __restrict__ Bt,
            void* __restrict__ Cout, int K, int ldc, int nbx, int cpx) {
  __shared__ __align__(16) u16 As0[128 * 32];
  __shared__ __align__(16) u16 As1[128 * 32];
  __shared__ __align__(16) u16 Bs0[256 * 32];
  __shared__ __align__(16) u16 Bs1[256 * 32];
  const int tid  = threadIdx.x;
  const int lane = tid & 63;
  const int wave = tid >> 6;          // 0..7
  const int wm = (wave & 1) * 64;
  const int wn = (wave >> 1) * 64;
  const int bid = blockIdx.x;
  const int lsw = (bid & 7) * cpx + (bid >> 3);
  const int by  = lsw / nbx;
  const int bx  = lsw - by * nbx;
  const size_t bm = (size_t)by * 128;
  const size_t bn = (size_t)bx * 256;

  // A staging: 128x32 (4096 elems), 1 gload/thread; eA = tid*8
  const int eA = tid * 8;
  const int rA = eA >> 5, cA = eA & 31;
  // B staging: 256x32 (8192 elems), 2 gloads/thread; rows 0-127 then 128-255
  const int rB0 = rA, cB0 = cA;
  const int rB1 = 128 + rA;

  const u16* Ab = A + bm * (size_t)K;
  const u16* Bb = Bt + bn * (size_t)K;

  f32x4 acc[4][4];
#pragma unroll
  for (int i = 0; i < 4; i++)
#pragma unroll
    for (int j = 0; j < 4; j++) acc[i][j] = (f32x4){0.f, 0.f, 0.f, 0.f};

#define STAGE(AS, BS, kk)                                              \
  do {                                                                 \
    gload16(Ab + (size_t)rA * K + (kk) + cA, &AS[wave * 512]);         \
    gload16(Bb + (size_t)rB0 * K + (kk) + cB0, &BS[wave * 512]);       \
    gload16(Bb + (size_t)rB1 * K + (kk) + cB0, &BS[4096 + wave * 512]);\
  } while (0)

#define COMPUTE(AS, BS)                                                          \
  do {                                                                           \
    const int fr = lane & 15, fk = (lane >> 4) * 8;                              \
    f16x8 av[4], bv[4];                                                          \
    _Pragma("unroll")                                                            \
    for (int i = 0; i < 4; i++) av[i] = *(const f16x8*)&AS[(wm + i * 16 + fr) * 32 + fk]; \
    _Pragma("unroll")                                                            \
    for (int j = 0; j < 4; j++) bv[j] = *(const f16x8*)&BS[(wn + j * 16 + fr) * 32 + fk]; \
    _Pragma("unroll")                                                            \
    for (int i = 0; i < 4; i++)                                                  \
      _Pragma("unroll")                                                          \
      for (int j = 0; j < 4; j++)                                                \
        acc[i][j] = __builtin_amdgcn_mfma_f32_16x16x32_f16(av[i], bv[j], acc[i][j], 0, 0, 0); \
  } while (0)

  STAGE(As0, Bs0, 0);
  __syncthreads();
  for (int k0 = 0; k0 < K; k0 += 64) {
    if (k0 + 32 < K) STAGE(As1, Bs1, k0 + 32);
    COMPUTE(As0, Bs0);
    __syncthreads();
    if (k0 + 64 < K) STAGE(As0, Bs0, k0 + 64);
    COMPUTE(As1, Bs1);
    __syncthreads();
  }
#undef STAGE
#undef COMPUTE

  // C/D layout: col = lane&15, row = (lane>>4)*4 + reg   [verified m89/m91]
  const int cr = (lane >> 4) * 4, ccol = lane & 15;
#pragma unroll
  for (int i = 0; i < 4; i++)
#pragma unroll
    for (int j = 0; j < 4; j++)
#pragma unroll
      for (int r = 0; r < 4; r++) {
        size_t row = bm + wm + i * 16 + cr + r;
        size_t col = bn + wn + j * 16 + ccol;
        if (OUT_F16) ((u16*)Cout)[row * ldc + col] = f2h(acc[i][j][r]);
        else         ((float*)Cout)[row * ldc + col] = acc[i][j][r];
      }
}

// ---------------- chunked SSM scan ----------------
// xzx: [M][NXPAD] f32 (x 0..4095 | B 4096..4127 | C 4128..4159 | pad). xzz: [M][4096] fp16.
__global__ __launch_bounds__(64)
void scan_pass1(const float* __restrict__ xzx, const float* __restrict__ conv_w,
                const float* __restrict__ A_log, const float* __restrict__ dt_bias,
                float* __restrict__ E) {
  const int bid = blockIdx.x;
  const int c   = bid & (NCHUNK - 1);
  const int bg  = bid >> 6;
  const int g   = bg & (GHEADS - 1);
  const int b   = bg >> 5;
  const int lane = threadIdx.x;
  const int ch0 = g * DH + lane, ch1 = ch0 + 64;

  const f32x4 w0 = ((const f32x4*)conv_w)[ch0];
  const f32x4 w1 = ((const f32x4*)conv_w)[ch1];
  const float dt = log1pf(expf(dt_bias[g]));
  const float Ac = -expf(A_log[g]);
  const float dA = expf(dt * Ac);

  const int l0 = c * SCHUNK;
  const float* base = xzx + (size_t)b * LSEQ * NXPAD;

  float xm3 = 0, xm2 = 0, xm1 = 0, Xm3 = 0, Xm2 = 0, Xm1 = 0;
#pragma unroll
  for (int j = 0; j < 3; j++) {
    int l = l0 - 3 + j;
    float v0 = 0, v1 = 0;
    if (l >= 0) {
      const float* rp = base + (size_t)l * NXPAD;
      v0 = rp[ch0]; v1 = rp[ch1];
    }
    if (j == 0) { xm3 = v0; Xm3 = v1; }
    else if (j == 1) { xm2 = v0; Xm2 = v1; }
    else { xm1 = v0; Xm1 = v1; }
  }
  float h0 = 0.f, h1 = 0.f;
  for (int t = 0; t < SCHUNK; t++) {
    const float* rp = base + (size_t)(l0 + t) * NXPAD;
    float xc0 = rp[ch0], xc1 = rp[ch1];
    float cx0 = w0[0] * xm3 + w0[1] * xm2 + w0[2] * xm1 + w0[3] * xc0;
    float cx1 = w1[0] * Xm3 + w1[1] * Xm2 + w1[2] * Xm1 + w1[3] * xc1;
    xm3 = xm2; xm2 = xm1; xm1 = xc0;
    Xm3 = Xm2; Xm2 = Xm1; Xm1 = xc1;
    float u = dt * rp[DGATE + g];
    h0 = dA * h0 + u * silu(cx0);
    h1 = dA * h1 + u * silu(cx1);
  }
  float* ep = E + (size_t)bid * DH;
  ep[lane] = h0; ep[lane + 64] = h1;
}

__global__ __launch_bounds__(64)
void scan_pass2(const float* __restrict__ E, float* __restrict__ Hs,
                const float* __restrict__ A_log, const float* __restrict__ dt_bias) {
  const int bg = blockIdx.x;
  const int g = bg & (GHEADS - 1);
  const int lane = threadIdx.x;
  const float dt = log1pf(expf(dt_bias[g]));
  const float Ac = -expf(A_log[g]);
  const float dAS = expf(dt * Ac * (float)SCHUNK);
  float h0 = 0.f, h1 = 0.f;
  for (int c = 0; c < NCHUNK; c++) {
    size_t idx = ((size_t)bg * NCHUNK + c) * DH;
    Hs[idx + lane] = h0; Hs[idx + lane + 64] = h1;
    h0 = dAS * h0 + E[idx + lane];
    h1 = dAS * h1 + E[idx + lane + 64];
  }
}

__global__ __launch_bounds__(64)
void scan_pass3(const float* __restrict__ xzx, const u16* __restrict__ xzz,
                const float* __restrict__ conv_w,
                const float* __restrict__ A_log, const float* __restrict__ dt_bias,
                const float* __restrict__ norm_w, const float* __restrict__ Hs,
                u16* __restrict__ gbuf) {
  const int bid = blockIdx.x;
  const int c   = bid & (NCHUNK - 1);
  const int bg  = bid >> 6;
  const int g   = bg & (GHEADS - 1);
  const int b   = bg >> 5;
  const int lane = threadIdx.x;
  const int ch0 = g * DH + lane, ch1 = ch0 + 64;

  const f32x4 wx0 = ((const f32x4*)conv_w)[ch0];
  const f32x4 wx1 = ((const f32x4*)conv_w)[ch1];
  const f32x4 wz0 = ((const f32x4*)conv_w)[DGATE + ch0];
  const f32x4 wz1 = ((const f32x4*)conv_w)[DGATE + ch1];
  const float nw0 = norm_w[lane], nw1 = norm_w[lane + 64];

  const float dt = log1pf(expf(dt_bias[g]));
  const float Ac = -expf(A_log[g]);
  const float dA = expf(dt * Ac);

  const int l0 = c * SCHUNK;
  const float* basex = xzx + (size_t)b * LSEQ * NXPAD;
  const u16*   basez = xzz + (size_t)b * LSEQ * DGATE;

  float xm3 = 0, xm2 = 0, xm1 = 0, Xm3 = 0, Xm2 = 0, Xm1 = 0;
  float zm3 = 0, zm2 = 0, zm1 = 0, Zm3 = 0, Zm2 = 0, Zm1 = 0;
#pragma unroll
  for (int j = 0; j < 3; j++) {
    int l = l0 - 3 + j;
    float vx0 = 0, vx1 = 0, vz0 = 0, vz1 = 0;
    if (l >= 0) {
      const float* rp = basex + (size_t)l * NXPAD;
      const u16*   rz = basez + (size_t)l * DGATE;
      vx0 = rp[ch0]; vx1 = rp[ch1];
      vz0 = h2f(rz[ch0]); vz1 = h2f(rz[ch1]);
    }
    if (j == 0) { xm3 = vx0; Xm3 = vx1; zm3 = vz0; Zm3 = vz1; }
    else if (j == 1) { xm2 = vx0; Xm2 = vx1; zm2 = vz0; Zm2 = vz1; }
    else { xm1 = vx0; Xm1 = vx1; zm1 = vz0; Zm1 = vz1; }
  }
  float h0 = Hs[(size_t)bid * DH + lane];
  float h1 = Hs[(size_t)bid * DH + lane + 64];
  for (int t = 0; t < SCHUNK; t++) {
    const int l = l0 + t;
    const float* rp = basex + (size_t)l * NXPAD;
    const u16*   rz = basez + (size_t)l * DGATE;
    float xc0 = rp[ch0], xc1 = rp[ch1];
    float zc0 = h2f(rz[ch0]), zc1 = h2f(rz[ch1]);
    float cx0 = wx0[0] * xm3 + wx0[1] * xm2 + wx0[2] * xm1 + wx0[3] * xc0;
    float cx1 = wx1[0] * Xm3 + wx1[1] * Xm2 + wx1[2] * Xm1 + wx1[3] * xc1;
    float cz0 = wz0[0] * zm3 + wz0[1] * zm2 + wz0[2] * zm1 + wz0[3] * zc0;
    float cz1 = wz1[0] * Zm3 + wz1[1] * Zm2 + wz1[2] * Zm1 + wz1[3] * zc1;
    xm3 = xm2; xm2 = xm1; xm1 = xc0;  Xm3 = Xm2; Xm2 = Xm1; Xm1 = xc1;
    zm3 = zm2; zm2 = zm1; zm1 = zc0;  Zm3 = Zm2; Zm2 = Zm1; Zm1 = zc1;
    float bcl = rp[DGATE + g];
    float ccl = rp[DGATE + 32 + g];
    float u = dt * bcl;
    h0 = dA * h0 + u * silu(cx0);
    h1 = dA * h1 + u * silu(cx1);
    float y0 = ccl * h0, y1 = ccl * h1;
    float ss = y0 * y0 + y1 * y1;
    ss += __shfl_xor(ss, 32); ss += __shfl_xor(ss, 16); ss += __shfl_xor(ss, 8);
    ss += __shfl_xor(ss, 4);  ss += __shfl_xor(ss, 2);  ss += __shfl_xor(ss, 1);
    const float sc = rsqrtf(ss * (1.0f / DH) + 1e-6f);
    u16* op = gbuf + (size_t)(b * LSEQ + l) * DGATE + g * DH;
    op[lane]      = f2h(y0 * sc * nw0 * silu(cz0));
    op[lane + 64] = f2h(y1 * sc * nw1 * silu(cz1));
  }
}

// ---------------- launch ----------------
extern "C" void kernel_launch(void* const* d_in, const int* in_sizes, int n_in,
                              void* d_out, int out_size, void* d_ws, size_t ws_size,
                              hipStream_t stream) {
  (void)in_sizes; (void)n_in; (void)out_size; (void)ws_size;
  const float* hs    = (const float*)d_in[0];
  const float* Wqkv  = (const float*)d_in[1];
  const float* Wb    = (const float*)d_in[2];
  const float* Wa    = (const float*)d_in[3];
  const float* convw = (const float*)d_in[4];
  const float* Wout  = (const float*)d_in[5];
  const float* normw = (const float*)d_in[6];
  const float* Alog  = (const float*)d_in[7];
  const float* dtb   = (const float*)d_in[8];
  float* out = (float*)d_out;

  // ws layout (~302 MB; <= 313 proven-safe):
  // [xzx 142.6 | xzz 67.1 | wcp 22.3 | wz 21.0 | pad 24 | wout 21.0 | E 2.1 | Hst 2.1]
  char* ws = (char*)d_ws;
  size_t off = 0;
  auto alloc = [&](size_t bytes) { void* p = ws + off; off += (bytes + 255) & ~(size_t)255; return p; };
  float* xzx    = (float*)alloc((size_t)MROWS * NXPAD * 4);      // 142.6 MB
  u16*   xzz    = (u16*)alloc((size_t)MROWS * DGATE * 2);        // 67.1 MB
  u16*   wcp    = (u16*)alloc((size_t)NXPAD * H_DIM * 2);        // 22.3 MB
  u16*   wz     = (u16*)alloc((size_t)DGATE * H_DIM * 2);        // 21.0 MB
  (void)alloc((size_t)24 << 20);                                 // 24 MB pad (gbuf tail)
  u16*   wout_h = (u16*)alloc((size_t)H_DIM * DGATE * 2);        // 21.0 MB
  float* E      = (float*)alloc((size_t)BSZ * GHEADS * NCHUNK * DH * 4);
  float* Hst    = (float*)alloc((size_t)BSZ * GHEADS * NCHUNK * DH * 4);
  // gbuf (67.1 MB) aliases [wcp|wz|pad] (67.3 MB): those are dead after the two
  // GEMM1s; pass3 (writer) launches strictly after them. Never touches wout.
  u16*   gbuf   = wcp;
  // hs_h (fp16, 41.9 MB) lives in d_out (83.9 MB), dead until GEMM2 overwrites it.
  u16*   hs_h   = (u16*)d_out;

  const int n4_hs = MROWS * H_DIM / 4;
  cast_f32_f16<<<(n4_hs + 255) / 256, 256, 0, stream>>>(hs, hs_h, n4_hs);
  build_wc<<<NXPAD + DGATE, 256, 0, stream>>>(Wqkv, Wb, Wa, wcp, wz);
  const int n4_wo = H_DIM * DGATE / 4;
  cast_f32_f16<<<(n4_wo + 255) / 256, 256, 0, stream>>>(Wout, wout_h, n4_wo);

  // GEMM1a: x|B|C -> f32 [8192, 4352].  grid 17*64=1088, cpx=136
  gemm_h<false><<<1088, 512, 0, stream>>>(hs_h, wcp, xzx, H_DIM, NXPAD, 17, 136);
  // GEMM1b: z -> fp16 [8192, 4096].     grid 16*64=1024, cpx=128
  gemm_h<true><<<1024, 512, 0, stream>>>(hs_h, wz, xzz, H_DIM, DGATE, 16, 128);

  scan_pass1<<<BSZ * GHEADS * NCHUNK, 64, 0, stream>>>(xzx, convw, Alog, dtb, E);
  scan_pass2<<<BSZ * GHEADS, 64, 0, stream>>>(E, Hst, Alog, dtb);
  scan_pass3<<<BSZ * GHEADS * NCHUNK, 64, 0, stream>>>(xzx, xzz, convw, Alog, dtb, normw, Hst, gbuf);

  // GEMM2: out = gated @ W_out^T -> f32 [8192, 2560].  grid 10*64=640, cpx=80
  gemm_h<false><<<640, 512, 0, stream>>>(gbuf, wout_h, out, DGATE, H_DIM, 10, 80);
}

// Round 7
// 854.477 us; speedup vs baseline: 1.8329x; 1.0069x over previous
//
#include <hip/hip_runtime.h>
#include <cstdint>
#include <cstddef>

// ---------------- problem geometry ----------------
#define H_DIM   2560
#define DINNER  8192
#define GHEADS  32
#define DGATE   4096
#define DH      128
#define BSZ     2
#define LSEQ    4096
#define MROWS   (BSZ*LSEQ)     // 8192 token rows
#define NXPAD   4352           // precise out width: 4096 x | 32 B | 32 C | 192 pad (=17*256)
#define NCHUNK  64
#define SCHUNK  (LSEQ/NCHUNK)  // 64

typedef __attribute__((ext_vector_type(4))) float    f32x4;
typedef __attribute__((ext_vector_type(8))) _Float16 f16x8;
typedef unsigned short u16;
typedef unsigned int   u32;

static __device__ __forceinline__ u16 f2h(float f) {
  _Float16 h = (_Float16)f;          // v_cvt_f16_f32, RNE
  union { _Float16 h; u16 u; } v; v.h = h; return v.u;
}
static __device__ __forceinline__ float h2f(u16 u) {
  union { u16 u; _Float16 h; } v; v.u = u; return (float)v.h;
}
static __device__ __forceinline__ float silu(float x) {
  return x / (1.0f + expf(-x));
}

// ---------------- prep casts (f32 -> fp16) ----------------
__global__ void cast_f32_f16(const float* __restrict__ in, u16* __restrict__ out, int n4) {
  int i = blockIdx.x * blockDim.x + threadIdx.x;
  if (i < n4) {
    f32x4 v = ((const f32x4*)in)[i];
    u32 p0 = (u32)f2h(v[0]) | ((u32)f2h(v[1]) << 16);
    u32 p1 = (u32)f2h(v[2]) | ((u32)f2h(v[3]) << 16);
    ((uint2*)out)[i] = make_uint2(p0, p1);
  }
}

// wcp rows (4352): 0..4095 = Wqkv x-rows, 4096..4127 = Wb, 4128..4159 = Wa, 4160..4351 = 0
// wz rows (4096): Wqkv z-rows 4096..8191
__global__ void build_wc(const float* __restrict__ Wqkv, const float* __restrict__ Wb,
                         const float* __restrict__ Wa, u16* __restrict__ wcp,
                         u16* __restrict__ wz) {
  int row = blockIdx.x;              // 0..8447
  if (row >= NXPAD) {
    const float* src = Wqkv + (size_t)(4096 + row - NXPAD) * H_DIM;
    u16* oh = wz + (size_t)(row - NXPAD) * H_DIM;
    for (int i = threadIdx.x; i < H_DIM / 4; i += blockDim.x) {
      f32x4 v = ((const f32x4*)src)[i];
      ((uint2*)oh)[i] = make_uint2((u32)f2h(v[0]) | ((u32)f2h(v[1]) << 16),
                                   (u32)f2h(v[2]) | ((u32)f2h(v[3]) << 16));
    }
    return;
  }
  const float* src = nullptr;
  if (row < 4096)              src = Wqkv + (size_t)row * H_DIM;
  else if (row < 4128)         src = Wb + (size_t)(row - 4096) * H_DIM;
  else if (row < 4160)         src = Wa + (size_t)(row - 4128) * H_DIM;
  u16* oh = wcp + (size_t)row * H_DIM;
  for (int i = threadIdx.x; i < H_DIM / 4; i += blockDim.x) {
    u32 p0 = 0, p1 = 0;
    if (src) {
      f32x4 v = ((const f32x4*)src)[i];
      p0 = (u32)f2h(v[0]) | ((u32)f2h(v[1]) << 16);
      p1 = (u32)f2h(v[2]) | ((u32)f2h(v[3]) << 16);
    }
    ((uint2*)oh)[i] = make_uint2(p0, p1);
  }
}

// ---------------- GEMM ----------------
static __device__ __forceinline__ void gload16(const u16* g, u16* l) {
  __builtin_amdgcn_global_load_lds(
      (const __attribute__((address_space(1))) u32*)g,
      (__attribute__((address_space(3))) u32*)l, 16, 0, 0);
}

#define BAR()    asm volatile("s_barrier" ::: "memory")
#define WAITV3() asm volatile("s_waitcnt vmcnt(3)" ::: "memory")
#define WAITV0() asm volatile("s_waitcnt vmcnt(0)" ::: "memory")

// Unified fp16 GEMM: C[m,n] = sum_k A[m,k]*Bt[n,k]. 128M x 256N tile, 512 thr
// (8 waves 2x4, per-wave 64x64, 4x4 16x16x32 frags). Double-buffered LDS with
// COUNTED vmcnt (T4): STAGE(buf,k+64) issued after the post-compute barrier;
// s_waitcnt vmcnt(3) waits only the PREVIOUS buffer's 3 loads -> each stage
// gets a full compute phase to land (never drain to 0 in the main loop).
// LDS XOR swizzle (T2, both-sides per rule #21): 16B slot ^= (row>>1)&3 —
// applied via pre-swizzled global source col + same XOR on fragment reads;
// turns the 8-way ds_read_b128 bank conflict into 2-way (free).
// K % 64 == 0. 1-D grid nbx*(M/128), XCD-grouped swizzle (cpx = grid/8).
template<bool OUT_F16>
__global__ __launch_bounds__(512)
void gemm_h(const u16* __restrict__ A, const u16* __restrict__ Bt,
            void* __restrict__ Cout, int K, int ldc, int nbx, int cpx) {
  __shared__ __align__(16) u16 As0[128 * 32];
  __shared__ __align__(16) u16 As1[128 * 32];
  __shared__ __align__(16) u16 Bs0[256 * 32];
  __shared__ __align__(16) u16 Bs1[256 * 32];
  const int tid  = threadIdx.x;
  const int lane = tid & 63;
  const int wave = tid >> 6;          // 0..7
  const int wm = (wave & 1) * 64;
  const int wn = (wave >> 1) * 64;
  const int bid = blockIdx.x;
  const int lsw = (bid & 7) * cpx + (bid >> 3);
  const int by  = lsw / nbx;
  const int bx  = lsw - by * nbx;
  const size_t bm = (size_t)by * 128;
  const size_t bn = (size_t)bx * 256;

  // staging coords: thread covers linear LDS slot tid*16B; row = tid>>2,
  // dest c8 = tid&3; SOURCE col pre-swizzled: c8 ^ ((row>>1)&3).
  // For B's second half (row+128) the mask is identical ((128+r)>>1 ≡ r>>1 mod 4).
  const int srow = tid >> 2;                                  // 0..127
  const int scol = (((tid & 3) ^ ((srow >> 1) & 3)) << 3);    // element col
  const u16* Ab = A + bm * (size_t)K;
  const u16* Bb = Bt + bn * (size_t)K;

  f32x4 acc[4][4];
#pragma unroll
  for (int i = 0; i < 4; i++)
#pragma unroll
    for (int j = 0; j < 4; j++) acc[i][j] = (f32x4){0.f, 0.f, 0.f, 0.f};

#define STAGE(AS, BS, kk)                                                \
  do {                                                                   \
    gload16(Ab + (size_t)srow * K + (kk) + scol, &AS[tid * 8]);          \
    gload16(Bb + (size_t)srow * K + (kk) + scol, &BS[tid * 8]);          \
    gload16(Bb + (size_t)(128 + srow) * K + (kk) + scol, &BS[4096 + tid * 8]); \
  } while (0)

#define COMPUTE(AS, BS)                                                           \
  do {                                                                            \
    const int fr = lane & 15;                                                     \
    const int fo = (((lane >> 4) ^ ((fr >> 1) & 3)) << 3);  /* swizzled k-off */  \
    f16x8 av[4], bv[4];                                                           \
    _Pragma("unroll")                                                             \
    for (int i = 0; i < 4; i++) av[i] = *(const f16x8*)&AS[(wm + i * 16 + fr) * 32 + fo]; \
    _Pragma("unroll")                                                             \
    for (int j = 0; j < 4; j++) bv[j] = *(const f16x8*)&BS[(wn + j * 16 + fr) * 32 + fo]; \
    __builtin_amdgcn_s_setprio(1);                                                \
    _Pragma("unroll")                                                             \
    for (int i = 0; i < 4; i++)                                                   \
      _Pragma("unroll")                                                           \
      for (int j = 0; j < 4; j++)                                                 \
        acc[i][j] = __builtin_amdgcn_mfma_f32_16x16x32_f16(av[i], bv[j], acc[i][j], 0, 0, 0); \
    __builtin_amdgcn_s_setprio(0);                                                \
  } while (0)

  STAGE(As0, Bs0, 0);            // 3 in flight
  STAGE(As1, Bs1, 32);           // 6 in flight
  WAITV3();                      // buf0's 3 landed (own wave)
  BAR();                         // => all waves' buf0 loads landed
  for (int k0 = 0; k0 < K; k0 += 64) {
    COMPUTE(As0, Bs0);
    BAR();                       // all waves done reading buf0
    if (k0 + 64 < K) { STAGE(As0, Bs0, k0 + 64); WAITV3(); }
    else             { WAITV0(); }
    BAR();                       // buf1 ready
    COMPUTE(As1, Bs1);
    BAR();                       // all waves done reading buf1
    if (k0 + 96 < K) { STAGE(As1, Bs1, k0 + 96); WAITV3(); }
    else             { WAITV0(); }
    BAR();                       // buf0 (next) ready
  }
#undef STAGE
#undef COMPUTE

  // C/D layout: col = lane&15, row = (lane>>4)*4 + reg   [verified m89/m91]
  const int cr = (lane >> 4) * 4, ccol = lane & 15;
#pragma unroll
  for (int i = 0; i < 4; i++)
#pragma unroll
    for (int j = 0; j < 4; j++)
#pragma unroll
      for (int r = 0; r < 4; r++) {
        size_t row = bm + wm + i * 16 + cr + r;
        size_t col = bn + wn + j * 16 + ccol;
        if (OUT_F16) ((u16*)Cout)[row * ldc + col] = f2h(acc[i][j][r]);
        else         ((float*)Cout)[row * ldc + col] = acc[i][j][r];
      }
}

// ---------------- chunked SSM scan ----------------
// xzx: [M][NXPAD] f32 (x 0..4095 | B 4096..4127 | C 4128..4159 | pad). xzz: [M][4096] fp16.
__global__ __launch_bounds__(64)
void scan_pass1(const float* __restrict__ xzx, const float* __restrict__ conv_w,
                const float* __restrict__ A_log, const float* __restrict__ dt_bias,
                float* __restrict__ E) {
  const int bid = blockIdx.x;
  const int c   = bid & (NCHUNK - 1);
  const int bg  = bid >> 6;
  const int g   = bg & (GHEADS - 1);
  const int b   = bg >> 5;
  const int lane = threadIdx.x;
  const int ch0 = g * DH + lane, ch1 = ch0 + 64;

  const f32x4 w0 = ((const f32x4*)conv_w)[ch0];
  const f32x4 w1 = ((const f32x4*)conv_w)[ch1];
  const float dt = log1pf(expf(dt_bias[g]));
  const float Ac = -expf(A_log[g]);
  const float dA = expf(dt * Ac);

  const int l0 = c * SCHUNK;
  const float* base = xzx + (size_t)b * LSEQ * NXPAD;

  float xm3 = 0, xm2 = 0, xm1 = 0, Xm3 = 0, Xm2 = 0, Xm1 = 0;
#pragma unroll
  for (int j = 0; j < 3; j++) {
    int l = l0 - 3 + j;
    float v0 = 0, v1 = 0;
    if (l >= 0) {
      const float* rp = base + (size_t)l * NXPAD;
      v0 = rp[ch0]; v1 = rp[ch1];
    }
    if (j == 0) { xm3 = v0; Xm3 = v1; }
    else if (j == 1) { xm2 = v0; Xm2 = v1; }
    else { xm1 = v0; Xm1 = v1; }
  }
  float h0 = 0.f, h1 = 0.f;
  for (int t = 0; t < SCHUNK; t++) {
    const float* rp = base + (size_t)(l0 + t) * NXPAD;
    float xc0 = rp[ch0], xc1 = rp[ch1];
    float cx0 = w0[0] * xm3 + w0[1] * xm2 + w0[2] * xm1 + w0[3] * xc0;
    float cx1 = w1[0] * Xm3 + w1[1] * Xm2 + w1[2] * Xm1 + w1[3] * xc1;
    xm3 = xm2; xm2 = xm1; xm1 = xc0;
    Xm3 = Xm2; Xm2 = Xm1; Xm1 = xc1;
    float u = dt * rp[DGATE + g];
    h0 = dA * h0 + u * silu(cx0);
    h1 = dA * h1 + u * silu(cx1);
  }
  float* ep = E + (size_t)bid * DH;
  ep[lane] = h0; ep[lane + 64] = h1;
}

__global__ __launch_bounds__(64)
void scan_pass2(const float* __restrict__ E, float* __restrict__ Hs,
                const float* __restrict__ A_log, const float* __restrict__ dt_bias) {
  const int bg = blockIdx.x;
  const int g = bg & (GHEADS - 1);
  const int lane = threadIdx.x;
  const float dt = log1pf(expf(dt_bias[g]));
  const float Ac = -expf(A_log[g]);
  const float dAS = expf(dt * Ac * (float)SCHUNK);
  float h0 = 0.f, h1 = 0.f;
  for (int c = 0; c < NCHUNK; c++) {
    size_t idx = ((size_t)bg * NCHUNK + c) * DH;
    Hs[idx + lane] = h0; Hs[idx + lane + 64] = h1;
    h0 = dAS * h0 + E[idx + lane];
    h1 = dAS * h1 + E[idx + lane + 64];
  }
}

__global__ __launch_bounds__(64)
void scan_pass3(const float* __restrict__ xzx, const u16* __restrict__ xzz,
                const float* __restrict__ conv_w,
                const float* __restrict__ A_log, const float* __restrict__ dt_bias,
                const float* __restrict__ norm_w, const float* __restrict__ Hs,
                u16* __restrict__ gbuf) {
  const int bid = blockIdx.x;
  const int c   = bid & (NCHUNK - 1);
  const int bg  = bid >> 6;
  const int g   = bg & (GHEADS - 1);
  const int b   = bg >> 5;
  const int lane = threadIdx.x;
  const int ch0 = g * DH + lane, ch1 = ch0 + 64;

  const f32x4 wx0 = ((const f32x4*)conv_w)[ch0];
  const f32x4 wx1 = ((const f32x4*)conv_w)[ch1];
  const f32x4 wz0 = ((const f32x4*)conv_w)[DGATE + ch0];
  const f32x4 wz1 = ((const f32x4*)conv_w)[DGATE + ch1];
  const float nw0 = norm_w[lane], nw1 = norm_w[lane + 64];

  const float dt = log1pf(expf(dt_bias[g]));
  const float Ac = -expf(A_log[g]);
  const float dA = expf(dt * Ac);

  const int l0 = c * SCHUNK;
  const float* basex = xzx + (size_t)b * LSEQ * NXPAD;
  const u16*   basez = xzz + (size_t)b * LSEQ * DGATE;

  float xm3 = 0, xm2 = 0, xm1 = 0, Xm3 = 0, Xm2 = 0, Xm1 = 0;
  float zm3 = 0, zm2 = 0, zm1 = 0, Zm3 = 0, Zm2 = 0, Zm1 = 0;
#pragma unroll
  for (int j = 0; j < 3; j++) {
    int l = l0 - 3 + j;
    float vx0 = 0, vx1 = 0, vz0 = 0, vz1 = 0;
    if (l >= 0) {
      const float* rp = basex + (size_t)l * NXPAD;
      const u16*   rz = basez + (size_t)l * DGATE;
      vx0 = rp[ch0]; vx1 = rp[ch1];
      vz0 = h2f(rz[ch0]); vz1 = h2f(rz[ch1]);
    }
    if (j == 0) { xm3 = vx0; Xm3 = vx1; zm3 = vz0; Zm3 = vz1; }
    else if (j == 1) { xm2 = vx0; Xm2 = vx1; zm2 = vz0; Zm2 = vz1; }
    else { xm1 = vx0; Xm1 = vx1; zm1 = vz0; Zm1 = vz1; }
  }
  float h0 = Hs[(size_t)bid * DH + lane];
  float h1 = Hs[(size_t)bid * DH + lane + 64];
  for (int t = 0; t < SCHUNK; t++) {
    const int l = l0 + t;
    const float* rp = basex + (size_t)l * NXPAD;
    const u16*   rz = basez + (size_t)l * DGATE;
    float xc0 = rp[ch0], xc1 = rp[ch1];
    float zc0 = h2f(rz[ch0]), zc1 = h2f(rz[ch1]);
    float cx0 = wx0[0] * xm3 + wx0[1] * xm2 + wx0[2] * xm1 + wx0[3] * xc0;
    float cx1 = wx1[0] * Xm3 + wx1[1] * Xm2 + wx1[2] * Xm1 + wx1[3] * xc1;
    float cz0 = wz0[0] * zm3 + wz0[1] * zm2 + wz0[2] * zm1 + wz0[3] * zc0;
    float cz1 = wz1[0] * Zm3 + wz1[1] * Zm2 + wz1[2] * Zm1 + wz1[3] * zc1;
    xm3 = xm2; xm2 = xm1; xm1 = xc0;  Xm3 = Xm2; Xm2 = Xm1; Xm1 = xc1;
    zm3 = zm2; zm2 = zm1; zm1 = zc0;  Zm3 = Zm2; Zm2 = Zm1; Zm1 = zc1;
    float bcl = rp[DGATE + g];
    float ccl = rp[DGATE + 32 + g];
    float u = dt * bcl;
    h0 = dA * h0 + u * silu(cx0);
    h1 = dA * h1 + u * silu(cx1);
    float y0 = ccl * h0, y1 = ccl * h1;
    float ss = y0 * y0 + y1 * y1;
    ss += __shfl_xor(ss, 32); ss += __shfl_xor(ss, 16); ss += __shfl_xor(ss, 8);
    ss += __shfl_xor(ss, 4);  ss += __shfl_xor(ss, 2);  ss += __shfl_xor(ss, 1);
    const float sc = rsqrtf(ss * (1.0f / DH) + 1e-6f);
    u16* op = gbuf + (size_t)(b * LSEQ + l) * DGATE + g * DH;
    op[lane]      = f2h(y0 * sc * nw0 * silu(cz0));
    op[lane + 64] = f2h(y1 * sc * nw1 * silu(cz1));
  }
}

// ---------------- launch ----------------
extern "C" void kernel_launch(void* const* d_in, const int* in_sizes, int n_in,
                              void* d_out, int out_size, void* d_ws, size_t ws_size,
                              hipStream_t stream) {
  (void)in_sizes; (void)n_in; (void)out_size; (void)ws_size;
  const float* hs    = (const float*)d_in[0];
  const float* Wqkv  = (const float*)d_in[1];
  const float* Wb    = (const float*)d_in[2];
  const float* Wa    = (const float*)d_in[3];
  const float* convw = (const float*)d_in[4];
  const float* Wout  = (const float*)d_in[5];
  const float* normw = (const float*)d_in[6];
  const float* Alog  = (const float*)d_in[7];
  const float* dtb   = (const float*)d_in[8];
  float* out = (float*)d_out;

  // ws layout (~302 MB; <= 313 proven-safe):
  // [xzx 142.6 | xzz 67.1 | wcp 22.3 | wz 21.0 | pad 24 | wout 21.0 | E 2.1 | Hst 2.1]
  char* ws = (char*)d_ws;
  size_t off = 0;
  auto alloc = [&](size_t bytes) { void* p = ws + off; off += (bytes + 255) & ~(size_t)255; return p; };
  float* xzx    = (float*)alloc((size_t)MROWS * NXPAD * 4);      // 142.6 MB
  u16*   xzz    = (u16*)alloc((size_t)MROWS * DGATE * 2);        // 67.1 MB
  u16*   wcp    = (u16*)alloc((size_t)NXPAD * H_DIM * 2);        // 22.3 MB
  u16*   wz     = (u16*)alloc((size_t)DGATE * H_DIM * 2);        // 21.0 MB
  (void)alloc((size_t)24 << 20);                                 // 24 MB pad (gbuf tail)
  u16*   wout_h = (u16*)alloc((size_t)H_DIM * DGATE * 2);        // 21.0 MB
  float* E      = (float*)alloc((size_t)BSZ * GHEADS * NCHUNK * DH * 4);
  float* Hst    = (float*)alloc((size_t)BSZ * GHEADS * NCHUNK * DH * 4);
  // gbuf (67.1 MB) aliases [wcp|wz|pad] (67.3 MB): those are dead after the two
  // GEMM1s; pass3 (writer) launches strictly after them. Never touches wout.
  u16*   gbuf   = wcp;
  // hs_h (fp16, 41.9 MB) lives in d_out (83.9 MB), dead until GEMM2 overwrites it.
  u16*   hs_h   = (u16*)d_out;

  const int n4_hs = MROWS * H_DIM / 4;
  cast_f32_f16<<<(n4_hs + 255) / 256, 256, 0, stream>>>(hs, hs_h, n4_hs);
  build_wc<<<NXPAD + DGATE, 256, 0, stream>>>(Wqkv, Wb, Wa, wcp, wz);
  const int n4_wo = H_DIM * DGATE / 4;
  cast_f32_f16<<<(n4_wo + 255) / 256, 256, 0, stream>>>(Wout, wout_h, n4_wo);

  // GEMM1a: x|B|C -> f32 [8192, 4352].  grid 17*64=1088, cpx=136
  gemm_h<false><<<1088, 512, 0, stream>>>(hs_h, wcp, xzx, H_DIM, NXPAD, 17, 136);
  // GEMM1b: z -> fp16 [8192, 4096].     grid 16*64=1024, cpx=128
  gemm_h<true><<<1024, 512, 0, stream>>>(hs_h, wz, xzz, H_DIM, DGATE, 16, 128);

  scan_pass1<<<BSZ * GHEADS * NCHUNK, 64, 0, stream>>>(xzx, convw, Alog, dtb, E);
  scan_pass2<<<BSZ * GHEADS, 64, 0, stream>>>(E, Hst, Alog, dtb);
  scan_pass3<<<BSZ * GHEADS * NCHUNK, 64, 0, stream>>>(xzx, xzz, convw, Alog, dtb, normw, Hst, gbuf);

  // GEMM2: out = gated @ W_out^T -> f32 [8192, 2560].  grid 10*64=640, cpx=80
  gemm_h<false><<<640, 512, 0, stream>>>(gbuf, wout_h, out, DGATE, H_DIM, 10, 80);
}

// Round 8
// 854.070 us; speedup vs baseline: 1.8338x; 1.0005x over previous
//
#include <hip/hip_runtime.h>
#include <cstdint>
#include <cstddef>

// ---------------- problem geometry ----------------
#define H_DIM   2560
#define DINNER  8192
#define GHEADS  32
#define DGATE   4096
#define DH      128
#define BSZ     2
#define LSEQ    4096
#define MROWS   (BSZ*LSEQ)     // 8192 token rows
#define NXPAD   4352           // precise out width: 4096 x | 32 B | 32 C | 192 pad (=17*256)
#define NCHUNK  64
#define SCHUNK  (LSEQ/NCHUNK)  // 64

typedef __attribute__((ext_vector_type(4))) float    f32x4;
typedef __attribute__((ext_vector_type(8))) _Float16 f16x8;
typedef unsigned short u16;
typedef unsigned int   u32;

static __device__ __forceinline__ u16 f2h(float f) {
  _Float16 h = (_Float16)f;          // v_cvt_f16_f32, RNE
  union { _Float16 h; u16 u; } v; v.h = h; return v.u;
}
static __device__ __forceinline__ float h2f(u16 u) {
  union { u16 u; _Float16 h; } v; v.u = u; return (float)v.h;
}
static __device__ __forceinline__ float silu(float x) {
  return x / (1.0f + expf(-x));
}

// ---------------- prep casts (f32 -> fp16) ----------------
__global__ void cast_f32_f16(const float* __restrict__ in, u16* __restrict__ out, int n4) {
  int i = blockIdx.x * blockDim.x + threadIdx.x;
  if (i < n4) {
    f32x4 v = ((const f32x4*)in)[i];
    u32 p0 = (u32)f2h(v[0]) | ((u32)f2h(v[1]) << 16);
    u32 p1 = (u32)f2h(v[2]) | ((u32)f2h(v[3]) << 16);
    ((uint2*)out)[i] = make_uint2(p0, p1);
  }
}

// wcp rows (4352): 0..4095 = Wqkv x-rows, 4096..4127 = Wb, 4128..4159 = Wa, 4160..4351 = 0
// wz rows (4096): Wqkv z-rows 4096..8191
__global__ void build_wc(const float* __restrict__ Wqkv, const float* __restrict__ Wb,
                         const float* __restrict__ Wa, u16* __restrict__ wcp,
                         u16* __restrict__ wz) {
  int row = blockIdx.x;              // 0..8447
  if (row >= NXPAD) {
    const float* src = Wqkv + (size_t)(4096 + row - NXPAD) * H_DIM;
    u16* oh = wz + (size_t)(row - NXPAD) * H_DIM;
    for (int i = threadIdx.x; i < H_DIM / 4; i += blockDim.x) {
      f32x4 v = ((const f32x4*)src)[i];
      ((uint2*)oh)[i] = make_uint2((u32)f2h(v[0]) | ((u32)f2h(v[1]) << 16),
                                   (u32)f2h(v[2]) | ((u32)f2h(v[3]) << 16));
    }
    return;
  }
  const float* src = nullptr;
  if (row < 4096)              src = Wqkv + (size_t)row * H_DIM;
  else if (row < 4128)         src = Wb + (size_t)(row - 4096) * H_DIM;
  else if (row < 4160)         src = Wa + (size_t)(row - 4128) * H_DIM;
  u16* oh = wcp + (size_t)row * H_DIM;
  for (int i = threadIdx.x; i < H_DIM / 4; i += blockDim.x) {
    u32 p0 = 0, p1 = 0;
    if (src) {
      f32x4 v = ((const f32x4*)src)[i];
      p0 = (u32)f2h(v[0]) | ((u32)f2h(v[1]) << 16);
      p1 = (u32)f2h(v[2]) | ((u32)f2h(v[3]) << 16);
    }
    ((uint2*)oh)[i] = make_uint2(p0, p1);
  }
}

// ---------------- GEMM: 256x256 8-phase (m201-style T2+T3+T4+T5) ----------------
static __device__ __forceinline__ void gload16(const u16* g, u16* l) {
  __builtin_amdgcn_global_load_lds(
      (const __attribute__((address_space(1))) u32*)g,
      (__attribute__((address_space(3))) u32*)l, 16, 0, 0);
}

#define BAR()    asm volatile("s_barrier" ::: "memory")
#define WAITV4() asm volatile("s_waitcnt vmcnt(4)" ::: "memory")
#define WAITV0() asm volatile("s_waitcnt vmcnt(0)" ::: "memory")

// C[m,n] = sum_k A[m,k]*Bt[n,k], fp16 in. BM=BN=256, BK=64 (2 K-tiles/iter),
// 512 thr = 8 waves (2M x 4N), per-wave 128x64 out (8x4 frags of 16x16x32).
// LDS 128KB: As[2]/Bs[2] = 2 dbuf x (256x64) each. Swizzle: 16B slot ^= row&7
// (write side: pre-swizzled global col, linear gload_lds dest; read side: same
// XOR) -> fragment ds_read_b128 spreads 8 lanes/bank-class = conflict-free.
// 8 phases/iter: {ds_read subtile | prefetch | barrier | MFMA(setprio) | barrier};
// refills issued >=2 barriers after region's last reader (P1:As1, P4:Bs0,
// P5:As0, P8:Bs1); vmcnt(4) ONLY at P4/P8 fences the next buffer cross-wave.
// K % 128 == 0. 1-D grid nbx*(M/256), XCD-grouped swizzle (cpx = grid/8).
template<bool OUT_F16>
__global__ __launch_bounds__(512, 2)
void gemm256(const u16* __restrict__ A, const u16* __restrict__ Bt,
             void* __restrict__ Cout, int K, int ldc, int nbx, int cpx) {
  __shared__ __align__(16) u16 As[2][256 * 64];
  __shared__ __align__(16) u16 Bs[2][256 * 64];
  const int tid  = threadIdx.x;
  const int lane = tid & 63;
  const int wave = tid >> 6;          // 0..7
  const int wm   = wave & 1;          // m half (128 rows)
  const int wn   = wave >> 1;         // n quarter (64 cols)
  const int bid  = blockIdx.x;
  const int lsw  = (bid & 7) * cpx + (bid >> 3);
  const int by   = lsw / nbx;
  const int bx   = lsw - by * nbx;
  const u16* Ab = A  + (size_t)by * 256 * K;
  const u16* Bb = Bt + (size_t)bx * 256 * K;

  // staging: thread covers granules g = q*512+tid (q=0..3) of a 256x64 operand;
  // row = g>>3 = q*64 + (tid>>3), dest slot = tid&7; source col pre-swizzled.
  const int srow0 = tid >> 3;
  const int scol  = (((tid & 7) ^ (srow0 & 7)) << 3);
  // fragment read coords
  const int fr  = lane & 15;
  const int kg  = lane >> 4;          // k granule within 32-k slice
  const int rsw = fr & 7;             // row&7 for all frag rows

  f32x4 acc[8][4];
#pragma unroll
  for (int i = 0; i < 8; i++)
#pragma unroll
    for (int j = 0; j < 4; j++) acc[i][j] = (f32x4){0.f, 0.f, 0.f, 0.f};

  f16x8 av[4], bv[4];

#define STAGEOP(dst, gb, kk)                                                     \
  do {                                                                           \
    _Pragma("unroll")                                                            \
    for (int q = 0; q < 4; q++)                                                  \
      gload16((gb) + (size_t)(srow0 + q * 64) * K + (kk) + scol,                 \
              (dst) + (size_t)(q * 512 + tid) * 8);                              \
  } while (0)

#define DSREAD_AV(d, qm, s)                                                      \
  do {                                                                           \
    _Pragma("unroll")                                                            \
    for (int i = 0; i < 4; i++)                                                  \
      av[i] = *(const f16x8*)&As[d][(wm * 128 + (qm) * 64 + i * 16 + fr) * 64 +  \
                                    ((((s) * 4 + kg) ^ rsw) << 3)];              \
  } while (0)

#define DSREAD_BV(d, s)                                                          \
  do {                                                                           \
    _Pragma("unroll")                                                            \
    for (int j = 0; j < 4; j++)                                                  \
      bv[j] = *(const f16x8*)&Bs[d][(wn * 64 + j * 16 + fr) * 64 +               \
                                    ((((s) * 4 + kg) ^ rsw) << 3)];              \
  } while (0)

#define MFMA16(qm)                                                               \
  do {                                                                           \
    __builtin_amdgcn_s_setprio(1);                                               \
    _Pragma("unroll")                                                            \
    for (int i = 0; i < 4; i++)                                                  \
      _Pragma("unroll")                                                          \
      for (int j = 0; j < 4; j++)                                                \
        acc[(qm) * 4 + i][j] =                                                   \
            __builtin_amdgcn_mfma_f32_16x16x32_f16(av[i], bv[j],                 \
                                                   acc[(qm) * 4 + i][j], 0, 0, 0);\
    __builtin_amdgcn_s_setprio(0);                                               \
  } while (0)

  const int T = K >> 7;               // iterations; each covers 2 K-tiles of 64
  // prologue: "virtual iter -1" issues: P4:Bs0<-KT0.B, P5:As0<-KT0.A, P8:Bs1<-KT1.B
  STAGEOP(&Bs[0][0], Bb, 0);
  STAGEOP(&As[0][0], Ab, 0);
  STAGEOP(&Bs[1][0], Bb, 64);
  WAITV4();                            // KT0 (8 oldest) landed; KT1.B may fly
  BAR();

  for (int it = 0; it < T; ++it) {
    const int k0 = it << 7;
    const bool lastit = (it == T - 1);
    // ---- P1: dbuf0 qm0 s0; issue As1 <- KT(2it+1).A ----
    DSREAD_BV(0, 0); DSREAD_AV(0, 0, 0);
    STAGEOP(&As[1][0], Ab, k0 + 64);
    BAR(); MFMA16(0); BAR();
    // ---- P2: dbuf0 qm1 s0 (bv reused) ----
    DSREAD_AV(0, 1, 0);
    BAR(); MFMA16(1); BAR();
    // ---- P3: dbuf0 qm0 s1 ----
    DSREAD_BV(0, 1); DSREAD_AV(0, 0, 1);
    BAR(); MFMA16(0); BAR();
    // ---- P4: dbuf0 qm1 s1; issue Bs0 <- KT(2it+2).B; fence dbuf1 ----
    DSREAD_AV(0, 1, 1);
    if (!lastit) { STAGEOP(&Bs[0][0], Bb, k0 + 128); WAITV4(); }
    else         { WAITV0(); }
    BAR(); MFMA16(1); BAR();
    // ---- P5: dbuf1 qm0 s0; issue As0 <- KT(2it+2).A ----
    DSREAD_BV(1, 0); DSREAD_AV(1, 0, 0);
    if (!lastit) STAGEOP(&As[0][0], Ab, k0 + 128);
    BAR(); MFMA16(0); BAR();
    // ---- P6: dbuf1 qm1 s0 ----
    DSREAD_AV(1, 1, 0);
    BAR(); MFMA16(1); BAR();
    // ---- P7: dbuf1 qm0 s1 ----
    DSREAD_BV(1, 1); DSREAD_AV(1, 0, 1);
    BAR(); MFMA16(0); BAR();
    // ---- P8: dbuf1 qm1 s1; issue Bs1 <- KT(2it+3).B; fence dbuf0 ----
    DSREAD_AV(1, 1, 1);
    if (!lastit) { STAGEOP(&Bs[1][0], Bb, k0 + 192); WAITV4(); }
    BAR(); MFMA16(1); BAR();
  }
#undef STAGEOP
#undef DSREAD_AV
#undef DSREAD_BV
#undef MFMA16

  // C/D layout: col = lane&15, row = (lane>>4)*4 + reg   [verified m89/m91]
  const int cr = (lane >> 4) * 4, ccol = lane & 15;
#pragma unroll
  for (int mf = 0; mf < 8; mf++)
#pragma unroll
    for (int nf = 0; nf < 4; nf++)
#pragma unroll
      for (int r = 0; r < 4; r++) {
        size_t row = (size_t)by * 256 + wm * 128 + mf * 16 + cr + r;
        size_t col = (size_t)bx * 256 + wn * 64 + nf * 16 + ccol;
        if (OUT_F16) ((u16*)Cout)[row * ldc + col] = f2h(acc[mf][nf][r]);
        else         ((float*)Cout)[row * ldc + col] = acc[mf][nf][r];
      }
}

// ---------------- chunked SSM scan ----------------
// xzx: [M][NXPAD] f32 (x 0..4095 | B 4096..4127 | C 4128..4159 | pad). xzz: [M][4096] fp16.
__global__ __launch_bounds__(64)
void scan_pass1(const float* __restrict__ xzx, const float* __restrict__ conv_w,
                const float* __restrict__ A_log, const float* __restrict__ dt_bias,
                float* __restrict__ E) {
  const int bid = blockIdx.x;
  const int c   = bid & (NCHUNK - 1);
  const int bg  = bid >> 6;
  const int g   = bg & (GHEADS - 1);
  const int b   = bg >> 5;
  const int lane = threadIdx.x;
  const int ch0 = g * DH + lane, ch1 = ch0 + 64;

  const f32x4 w0 = ((const f32x4*)conv_w)[ch0];
  const f32x4 w1 = ((const f32x4*)conv_w)[ch1];
  const float dt = log1pf(expf(dt_bias[g]));
  const float Ac = -expf(A_log[g]);
  const float dA = expf(dt * Ac);

  const int l0 = c * SCHUNK;
  const float* base = xzx + (size_t)b * LSEQ * NXPAD;

  float xm3 = 0, xm2 = 0, xm1 = 0, Xm3 = 0, Xm2 = 0, Xm1 = 0;
#pragma unroll
  for (int j = 0; j < 3; j++) {
    int l = l0 - 3 + j;
    float v0 = 0, v1 = 0;
    if (l >= 0) {
      const float* rp = base + (size_t)l * NXPAD;
      v0 = rp[ch0]; v1 = rp[ch1];
    }
    if (j == 0) { xm3 = v0; Xm3 = v1; }
    else if (j == 1) { xm2 = v0; Xm2 = v1; }
    else { xm1 = v0; Xm1 = v1; }
  }
  float h0 = 0.f, h1 = 0.f;
  for (int t = 0; t < SCHUNK; t++) {
    const float* rp = base + (size_t)(l0 + t) * NXPAD;
    float xc0 = rp[ch0], xc1 = rp[ch1];
    float cx0 = w0[0] * xm3 + w0[1] * xm2 + w0[2] * xm1 + w0[3] * xc0;
    float cx1 = w1[0] * Xm3 + w1[1] * Xm2 + w1[2] * Xm1 + w1[3] * xc1;
    xm3 = xm2; xm2 = xm1; xm1 = xc0;
    Xm3 = Xm2; Xm2 = Xm1; Xm1 = xc1;
    float u = dt * rp[DGATE + g];
    h0 = dA * h0 + u * silu(cx0);
    h1 = dA * h1 + u * silu(cx1);
  }
  float* ep = E + (size_t)bid * DH;
  ep[lane] = h0; ep[lane + 64] = h1;
}

__global__ __launch_bounds__(64)
void scan_pass2(const float* __restrict__ E, float* __restrict__ Hs,
                const float* __restrict__ A_log, const float* __restrict__ dt_bias) {
  const int bg = blockIdx.x;
  const int g = bg & (GHEADS - 1);
  const int lane = threadIdx.x;
  const float dt = log1pf(expf(dt_bias[g]));
  const float Ac = -expf(A_log[g]);
  const float dAS = expf(dt * Ac * (float)SCHUNK);
  float h0 = 0.f, h1 = 0.f;
  for (int c = 0; c < NCHUNK; c++) {
    size_t idx = ((size_t)bg * NCHUNK + c) * DH;
    Hs[idx + lane] = h0; Hs[idx + lane + 64] = h1;
    h0 = dAS * h0 + E[idx + lane];
    h1 = dAS * h1 + E[idx + lane + 64];
  }
}

__global__ __launch_bounds__(64)
void scan_pass3(const float* __restrict__ xzx, const u16* __restrict__ xzz,
                const float* __restrict__ conv_w,
                const float* __restrict__ A_log, const float* __restrict__ dt_bias,
                const float* __restrict__ norm_w, const float* __restrict__ Hs,
                u16* __restrict__ gbuf) {
  const int bid = blockIdx.x;
  const int c   = bid & (NCHUNK - 1);
  const int bg  = bid >> 6;
  const int g   = bg & (GHEADS - 1);
  const int b   = bg >> 5;
  const int lane = threadIdx.x;
  const int ch0 = g * DH + lane, ch1 = ch0 + 64;

  const f32x4 wx0 = ((const f32x4*)conv_w)[ch0];
  const f32x4 wx1 = ((const f32x4*)conv_w)[ch1];
  const f32x4 wz0 = ((const f32x4*)conv_w)[DGATE + ch0];
  const f32x4 wz1 = ((const f32x4*)conv_w)[DGATE + ch1];
  const float nw0 = norm_w[lane], nw1 = norm_w[lane + 64];

  const float dt = log1pf(expf(dt_bias[g]));
  const float Ac = -expf(A_log[g]);
  const float dA = expf(dt * Ac);

  const int l0 = c * SCHUNK;
  const float* basex = xzx + (size_t)b * LSEQ * NXPAD;
  const u16*   basez = xzz + (size_t)b * LSEQ * DGATE;

  float xm3 = 0, xm2 = 0, xm1 = 0, Xm3 = 0, Xm2 = 0, Xm1 = 0;
  float zm3 = 0, zm2 = 0, zm1 = 0, Zm3 = 0, Zm2 = 0, Zm1 = 0;
#pragma unroll
  for (int j = 0; j < 3; j++) {
    int l = l0 - 3 + j;
    float vx0 = 0, vx1 = 0, vz0 = 0, vz1 = 0;
    if (l >= 0) {
      const float* rp = basex + (size_t)l * NXPAD;
      const u16*   rz = basez + (size_t)l * DGATE;
      vx0 = rp[ch0]; vx1 = rp[ch1];
      vz0 = h2f(rz[ch0]); vz1 = h2f(rz[ch1]);
    }
    if (j == 0) { xm3 = vx0; Xm3 = vx1; zm3 = vz0; Zm3 = vz1; }
    else if (j == 1) { xm2 = vx0; Xm2 = vx1; zm2 = vz0; Zm2 = vz1; }
    else { xm1 = vx0; Xm1 = vx1; zm1 = vz0; Zm1 = vz1; }
  }
  float h0 = Hs[(size_t)bid * DH + lane];
  float h1 = Hs[(size_t)bid * DH + lane + 64];
  for (int t = 0; t < SCHUNK; t++) {
    const int l = l0 + t;
    const float* rp = basex + (size_t)l * NXPAD;
    const u16*   rz = basez + (size_t)l * DGATE;
    float xc0 = rp[ch0], xc1 = rp[ch1];
    float zc0 = h2f(rz[ch0]), zc1 = h2f(rz[ch1]);
    float cx0 = wx0[0] * xm3 + wx0[1] * xm2 + wx0[2] * xm1 + wx0[3] * xc0;
    float cx1 = wx1[0] * Xm3 + wx1[1] * Xm2 + wx1[2] * Xm1 + wx1[3] * xc1;
    float cz0 = wz0[0] * zm3 + wz0[1] * zm2 + wz0[2] * zm1 + wz0[3] * zc0;
    float cz1 = wz1[0] * Zm3 + wz1[1] * Zm2 + wz1[2] * Zm1 + wz1[3] * zc1;
    xm3 = xm2; xm2 = xm1; xm1 = xc0;  Xm3 = Xm2; Xm2 = Xm1; Xm1 = xc1;
    zm3 = zm2; zm2 = zm1; zm1 = zc0;  Zm3 = Zm2; Zm2 = Zm1; Zm1 = zc1;
    float bcl = rp[DGATE + g];
    float ccl = rp[DGATE + 32 + g];
    float u = dt * bcl;
    h0 = dA * h0 + u * silu(cx0);
    h1 = dA * h1 + u * silu(cx1);
    float y0 = ccl * h0, y1 = ccl * h1;
    float ss = y0 * y0 + y1 * y1;
    ss += __shfl_xor(ss, 32); ss += __shfl_xor(ss, 16); ss += __shfl_xor(ss, 8);
    ss += __shfl_xor(ss, 4);  ss += __shfl_xor(ss, 2);  ss += __shfl_xor(ss, 1);
    const float sc = rsqrtf(ss * (1.0f / DH) + 1e-6f);
    u16* op = gbuf + (size_t)(b * LSEQ + l) * DGATE + g * DH;
    op[lane]      = f2h(y0 * sc * nw0 * silu(cz0));
    op[lane + 64] = f2h(y1 * sc * nw1 * silu(cz1));
  }
}

// ---------------- launch ----------------
extern "C" void kernel_launch(void* const* d_in, const int* in_sizes, int n_in,
                              void* d_out, int out_size, void* d_ws, size_t ws_size,
                              hipStream_t stream) {
  (void)in_sizes; (void)n_in; (void)out_size; (void)ws_size;
  const float* hs    = (const float*)d_in[0];
  const float* Wqkv  = (const float*)d_in[1];
  const float* Wb    = (const float*)d_in[2];
  const float* Wa    = (const float*)d_in[3];
  const float* convw = (const float*)d_in[4];
  const float* Wout  = (const float*)d_in[5];
  const float* normw = (const float*)d_in[6];
  const float* Alog  = (const float*)d_in[7];
  const float* dtb   = (const float*)d_in[8];
  float* out = (float*)d_out;

  // ws layout (~302 MB; <= 313 proven-safe):
  // [xzx 142.6 | xzz 67.1 | wcp 22.3 | wz 21.0 | pad 24 | wout 21.0 | E 2.1 | Hst 2.1]
  char* ws = (char*)d_ws;
  size_t off = 0;
  auto alloc = [&](size_t bytes) { void* p = ws + off; off += (bytes + 255) & ~(size_t)255; return p; };
  float* xzx    = (float*)alloc((size_t)MROWS * NXPAD * 4);      // 142.6 MB
  u16*   xzz    = (u16*)alloc((size_t)MROWS * DGATE * 2);        // 67.1 MB
  u16*   wcp    = (u16*)alloc((size_t)NXPAD * H_DIM * 2);        // 22.3 MB
  u16*   wz     = (u16*)alloc((size_t)DGATE * H_DIM * 2);        // 21.0 MB
  (void)alloc((size_t)24 << 20);                                 // 24 MB pad (gbuf tail)
  u16*   wout_h = (u16*)alloc((size_t)H_DIM * DGATE * 2);        // 21.0 MB
  float* E      = (float*)alloc((size_t)BSZ * GHEADS * NCHUNK * DH * 4);
  float* Hst    = (float*)alloc((size_t)BSZ * GHEADS * NCHUNK * DH * 4);
  // gbuf (67.1 MB) aliases [wcp|wz|pad] (67.3 MB): those are dead after the two
  // GEMM1s; pass3 (writer) launches strictly after them. Never touches wout.
  u16*   gbuf   = wcp;
  // hs_h (fp16, 41.9 MB) lives in d_out (83.9 MB), dead until GEMM2 overwrites it.
  u16*   hs_h   = (u16*)d_out;

  const int n4_hs = MROWS * H_DIM / 4;
  cast_f32_f16<<<(n4_hs + 255) / 256, 256, 0, stream>>>(hs, hs_h, n4_hs);
  build_wc<<<NXPAD + DGATE, 256, 0, stream>>>(Wqkv, Wb, Wa, wcp, wz);
  const int n4_wo = H_DIM * DGATE / 4;
  cast_f32_f16<<<(n4_wo + 255) / 256, 256, 0, stream>>>(Wout, wout_h, n4_wo);

  // GEMM1a: x|B|C -> f32 [8192, 4352].  grid 32x17=544, cpx=68
  gemm256<false><<<544, 512, 0, stream>>>(hs_h, wcp, xzx, H_DIM, NXPAD, 17, 68);
  // GEMM1b: z -> fp16 [8192, 4096].     grid 32x16=512, cpx=64
  gemm256<true><<<512, 512, 0, stream>>>(hs_h, wz, xzz, H_DIM, DGATE, 16, 64);

  scan_pass1<<<BSZ * GHEADS * NCHUNK, 64, 0, stream>>>(xzx, convw, Alog, dtb, E);
  scan_pass2<<<BSZ * GHEADS, 64, 0, stream>>>(E, Hst, Alog, dtb);
  scan_pass3<<<BSZ * GHEADS * NCHUNK, 64, 0, stream>>>(xzx, xzz, convw, Alog, dtb, normw, Hst, gbuf);

  // GEMM2: out = gated @ W_out^T -> f32 [8192, 2560].  grid 32x10=320, cpx=40
  gemm256<false><<<320, 512, 0, stream>>>(gbuf, wout_h, out, DGATE, H_DIM, 10, 40);
}